// Round 1
// baseline (9427.652 us; speedup 1.0000x reference)
//
#include <hip/hip_runtime.h>

#define BB   32
#define SS   512
#define DDIM 512
#define HH   8
#define DKK  64
#define DFFN 2048
#define MR   (BB*SS)   // 16384 rows

// ---------- bf16 helpers ----------
__device__ __forceinline__ unsigned int packbf2(float x, float y) {
  unsigned int ux = __float_as_uint(x);
  unsigned int uy = __float_as_uint(y);
  unsigned int hx = (ux + 0x7FFFu + ((ux >> 16) & 1u)) >> 16;
  unsigned int hy = (uy + 0x7FFFu + ((uy >> 16) & 1u)) >> 16;
  return hx | (hy << 16);
}
__device__ __forceinline__ float bflo(unsigned int u) { return __uint_as_float(u << 16); }
__device__ __forceinline__ float bfhi(unsigned int u) { return __uint_as_float(u & 0xFFFF0000u); }

// ---------- tiled f32 GEMM: C[M,N] = A[M,K] @ B[K,N] (+bias) (+accum) (+relu) ----------
// A row stride = K. B row stride = ldb. C row stride = ldc.
__global__ __launch_bounds__(256) void gemm_f32(
    const float* __restrict__ A, const float* __restrict__ Bm,
    const float* __restrict__ bias, float* __restrict__ C,
    int M, int N, int K, int ldb, int ldc, int relu, int accum)
{
  __shared__ float As[32][68];  // k-major: As[kk][r]
  __shared__ float Bs[32][68];  // k-major: Bs[kk][c]
  const int t  = threadIdx.x;
  const int tx = t & 15, ty = t >> 4;
  const int row0 = blockIdx.y * 64, col0 = blockIdx.x * 64;
  float acc[4][4] = {{0.f}};

  for (int k0 = 0; k0 < K; k0 += 32) {
    // stage A tile 64x32 (coalesced float4 loads, scatter to k-major)
    #pragma unroll
    for (int l = 0; l < 2; ++l) {
      int idx = t + l * 256;          // 0..511
      int r   = idx >> 3;             // 0..63
      int c4  = idx & 7;              // 0..7
      float4 v = *(const float4*)(A + (size_t)(row0 + r) * K + k0 + c4 * 4);
      As[c4*4+0][r] = v.x; As[c4*4+1][r] = v.y;
      As[c4*4+2][r] = v.z; As[c4*4+3][r] = v.w;
    }
    // stage B tile 32x64
    #pragma unroll
    for (int l = 0; l < 2; ++l) {
      int idx = t + l * 256;
      int r   = idx >> 4;             // 0..31
      int c4  = idx & 15;             // 0..15
      float4 v = *(const float4*)(Bm + (size_t)(k0 + r) * ldb + col0 + c4 * 4);
      Bs[r][c4*4+0] = v.x; Bs[r][c4*4+1] = v.y;
      Bs[r][c4*4+2] = v.z; Bs[r][c4*4+3] = v.w;
    }
    __syncthreads();
    #pragma unroll
    for (int kk = 0; kk < 32; ++kk) {
      float4 a4 = *(const float4*)(&As[kk][ty * 4]);
      float4 b4 = *(const float4*)(&Bs[kk][tx * 4]);
      float ar[4] = {a4.x, a4.y, a4.z, a4.w};
      float bc[4] = {b4.x, b4.y, b4.z, b4.w};
      #pragma unroll
      for (int rr = 0; rr < 4; ++rr)
        #pragma unroll
        for (int cc = 0; cc < 4; ++cc)
          acc[rr][cc] = fmaf(ar[rr], bc[cc], acc[rr][cc]);
    }
    __syncthreads();
  }

  #pragma unroll
  for (int rr = 0; rr < 4; ++rr) {
    int r = row0 + ty * 4 + rr;
    #pragma unroll
    for (int cc = 0; cc < 4; ++cc) {
      int c = col0 + tx * 4 + cc;
      float v = acc[rr][cc];
      if (bias)  v += bias[c];
      if (accum) v += C[(size_t)r * ldc + c];
      if (relu)  v = fmaxf(v, 0.f);
      C[(size_t)r * ldc + c] = v;
    }
  }
}

// ---------- block helpers (512 threads = 8 waves) ----------
__device__ __forceinline__ float block_max(float v, float* red, int lane, int wid) {
  #pragma unroll
  for (int off = 32; off > 0; off >>= 1) v = fmaxf(v, __shfl_xor(v, off, 64));
  if (lane == 0) red[wid] = v;
  __syncthreads();
  float m = red[0];
  #pragma unroll
  for (int w = 1; w < 8; ++w) m = fmaxf(m, red[w]);
  __syncthreads();
  return m;
}
__device__ __forceinline__ float block_sum(float v, float* red, int lane, int wid) {
  #pragma unroll
  for (int off = 32; off > 0; off >>= 1) v += __shfl_xor(v, off, 64);
  if (lane == 0) red[wid] = v;
  __syncthreads();
  float s = 0.f;
  #pragma unroll
  for (int w = 0; w < 8; ++w) s += red[w];
  __syncthreads();
  return s;
}
__device__ __forceinline__ void block_scan(float v, float* red, int lane, int wid,
                                           float& incl, float& total) {
  float x = v;
  #pragma unroll
  for (int off = 1; off < 64; off <<= 1) {
    float n = __shfl_up(x, off, 64);
    if (lane >= off) x += n;
  }
  if (lane == 63) red[wid] = x;
  __syncthreads();
  float woff = 0.f, tot = 0.f;
  #pragma unroll
  for (int w = 0; w < 8; ++w) {
    float r = red[w];
    tot += r;
    if (w < wid) woff += r;
  }
  incl  = woff + x;
  total = tot;
  __syncthreads();
}

// ---------- attention with distance-decay rescoring ----------
// qk: [B,S,D] projection used as BOTH q and k. vbuf: [B,S,D] v projection.
// out: [B,S,D]  (may alias vbuf: each block writes only its own (b,h) slice,
//                and vbuf is only read during LDS staging before any write)
// mask_excl: 0 -> valid j<=i ; 1 -> valid j<i.  zero_pad: zero row i==0.
__global__ __launch_bounds__(512) void attn_kernel(
    const float* __restrict__ qk, const float* __restrict__ vbuf,
    const float* __restrict__ gam, float* __restrict__ out,
    int mask_excl, int zero_pad)
{
  __shared__ unsigned int kT[32][513];  // packed bf16x2, k-pair-major: (2m,2m+1, j)
  __shared__ unsigned int vS[512][32];  // packed bf16x2: v[j][2m],v[j][2m+1]
  __shared__ float qrow[64];
  __shared__ float pbuf[512];
  __shared__ float red[8];
  __shared__ float pvp[8][64];

  const int t    = threadIdx.x;
  const int lane = t & 63, wid = t >> 6;
  const int bh   = blockIdx.x;
  const int b    = bh >> 3, h = bh & 7;
  const size_t base = (size_t)b * SS * DDIM + (size_t)h * DKK;

  // gamma = -softplus(gam[h]) (stable)
  float g  = gam[h];
  float sp = (g > 0.f) ? (g + log1pf(__expf(-g))) : log1pf(__expf(g));
  const float gamma = -sp;

  // stage K (transposed, packed) and V (packed)
  for (int it = 0; it < 32; ++it) {
    int idx = it * 512 + t;
    int j = idx >> 5, m = idx & 31;
    float2 kf = *(const float2*)(qk + base + (size_t)j * DDIM + 2 * m);
    kT[m][j] = packbf2(kf.x, kf.y);
  }
  for (int it = 0; it < 32; ++it) {
    int idx = it * 512 + t;
    int j = idx >> 5, m = idx & 31;
    float2 vf = *(const float2*)(vbuf + base + (size_t)j * DDIM + 2 * m);
    vS[j][m] = packbf2(vf.x, vf.y);
  }
  __syncthreads();

  const int j = t;  // thread owns column j
  for (int i = 0; i < SS; ++i) {
    if (t < 64) qrow[t] = qk[base + (size_t)i * DDIM + t] * 0.125f; // 1/sqrt(64)
    __syncthreads();

    const int  nvalid = mask_excl ? i : (i + 1);
    const bool valid  = (j < nvalid);

    // scores: s_j = (q_i . k_j)/8
    float s = 0.f;
    #pragma unroll
    for (int m = 0; m < 32; ++m) {
      unsigned int u = kT[m][j];
      s = fmaf(qrow[2 * m],     bflo(u), s);
      s = fmaf(qrow[2 * m + 1], bfhi(u), s);
    }

    // softmax 1 (masked)
    float sm = valid ? s : -3.0e38f;
    float M1 = block_max(sm, red, lane, wid);
    float e1 = valid ? __expf(s - M1) : 0.f;
    float S1 = block_sum(e1, red, lane, wid);
    float p1 = (nvalid > 0) ? (e1 / S1) : 0.f;

    // cumsum along j
    float incl, total;
    block_scan(p1, red, lane, wid, incl, total);

    // distance decay
    float rem   = total - incl;
    float posij = fabsf((float)(i - j));
    float dist  = sqrtf(fmaxf(rem * posij, 0.f));
    float eff   = __expf(dist * gamma);
    eff = fminf(fmaxf(eff, 1e-5f), 1e5f);

    // rescored softmax 2
    float s2 = valid ? (s * eff) : -3.0e38f;
    float M2 = block_max(s2, red, lane, wid);
    float e2 = valid ? __expf(s2 - M2) : 0.f;
    float S2 = block_sum(e2, red, lane, wid);
    float p2 = (nvalid > 0) ? (e2 / S2) : (1.0f / (float)SS);
    if (zero_pad && i == 0) p2 = 0.f;
    pbuf[j] = p2;
    __syncthreads();

    // PV: wave wid handles j in [wid*64, wid*64+64), lane = output dim d
    const int d = lane;
    float acc = 0.f;
    #pragma unroll
    for (int jj = 0; jj < 64; ++jj) {
      int jq = wid * 64 + jj;
      float pj = pbuf[jq];
      unsigned int u = vS[jq][d >> 1];
      float vv = (d & 1) ? bfhi(u) : bflo(u);
      acc = fmaf(pj, vv, acc);
    }
    pvp[wid][d] = acc;
    __syncthreads();
    if (t < 64) {
      float o = 0.f;
      #pragma unroll
      for (int g2 = 0; g2 < 8; ++g2) o += pvp[g2][t];
      out[base + (size_t)i * DDIM + t] = o;
    }
    __syncthreads();
  }
}

// ---------- fused residual + LayerNorm: out = LN(a + b) * g + be ----------
__global__ __launch_bounds__(256) void ln_kernel(
    const float* __restrict__ a, const float* __restrict__ bsrc,
    const float* __restrict__ g, const float* __restrict__ be,
    float* __restrict__ out)
{
  const int lane = threadIdx.x & 63, w = threadIdx.x >> 6;
  const size_t row = (size_t)blockIdx.x * 4 + w;
  const float* pa = a    + row * DDIM;
  const float* pb = bsrc + row * DDIM;
  float v[8];
  float sum = 0.f;
  #pragma unroll
  for (int c = 0; c < 2; ++c) {
    float4 va = *(const float4*)(pa + c * 256 + lane * 4);
    float4 vb = *(const float4*)(pb + c * 256 + lane * 4);
    v[c*4+0] = va.x + vb.x; v[c*4+1] = va.y + vb.y;
    v[c*4+2] = va.z + vb.z; v[c*4+3] = va.w + vb.w;
    sum += v[c*4+0] + v[c*4+1] + v[c*4+2] + v[c*4+3];
  }
  #pragma unroll
  for (int off = 32; off > 0; off >>= 1) sum += __shfl_xor(sum, off, 64);
  const float mean = sum * (1.f / 512.f);
  float var = 0.f;
  #pragma unroll
  for (int k = 0; k < 8; ++k) { float d = v[k] - mean; var = fmaf(d, d, var); }
  #pragma unroll
  for (int off = 32; off > 0; off >>= 1) var += __shfl_xor(var, off, 64);
  var *= (1.f / 512.f);
  const float inv = rsqrtf(var + 1e-5f);
  float* po = out + row * DDIM;
  #pragma unroll
  for (int c = 0; c < 2; ++c) {
    float4 gg = *(const float4*)(g  + c * 256 + lane * 4);
    float4 bb = *(const float4*)(be + c * 256 + lane * 4);
    float4 o;
    o.x = (v[c*4+0] - mean) * inv * gg.x + bb.x;
    o.y = (v[c*4+1] - mean) * inv * gg.y + bb.y;
    o.z = (v[c*4+2] - mean) * inv * gg.z + bb.z;
    o.w = (v[c*4+3] - mean) * inv * gg.w + bb.w;
    *(float4*)(po + c * 256 + lane * 4) = o;
  }
}

// ---------- orchestration ----------
extern "C" void kernel_launch(void* const* d_in, const int* in_sizes, int n_in,
                              void* d_out, int out_size, void* d_ws, size_t ws_size,
                              hipStream_t stream) {
  const float* qe  = (const float*)d_in[0];
  const float* qa  = (const float*)d_in[1];
  const float* Wk  = (const float*)d_in[2];
  const float* bk  = (const float*)d_in[3];
  const float* Wv  = (const float*)d_in[4];
  const float* bv  = (const float*)d_in[5];
  const float* Wo  = (const float*)d_in[6];
  const float* bo  = (const float*)d_in[7];
  const float* gm  = (const float*)d_in[8];
  const float* l1g = (const float*)d_in[9];
  const float* l1b = (const float*)d_in[10];
  const float* W1  = (const float*)d_in[11];
  const float* b1  = (const float*)d_in[12];
  const float* W2  = (const float*)d_in[13];
  const float* b2  = (const float*)d_in[14];
  const float* l2g = (const float*)d_in[15];
  const float* l2b = (const float*)d_in[16];

  float* ws = (float*)d_ws;
  const size_t RSZ = (size_t)MR * DDIM;  // 8.4M floats = 32MB
  float* R0 = ws;
  float* R1 = ws + RSZ;
  float* R2 = ws + 2 * RSZ;
  float* Y1 = ws + 3 * RSZ;
  float* X1 = ws + 4 * RSZ;

  auto gemm = [&](const float* A, const float* Bp, const float* bias, float* C,
                  int M, int N, int K, int ldb, int ldc, int relu, int accum) {
    dim3 grid(N / 64, M / 64);
    gemm_f32<<<grid, 256, 0, stream>>>(A, Bp, bias, C, M, N, K, ldb, ldc, relu, accum);
  };

  auto layer = [&](int li, const float* query, const float* values,
                   int excl, int zp, int pos, float* outp) {
    const float* Wk_l = Wk + (size_t)li * DDIM * DDIM;
    const float* bk_l = bk + (size_t)li * DDIM;
    const float* Wv_l = Wv + (size_t)li * DDIM * DDIM;
    const float* bv_l = bv + (size_t)li * DDIM;
    const float* Wo_l = Wo + (size_t)li * DDIM * DDIM;
    const float* bo_l = bo + (size_t)li * DDIM;
    const float* gm_l = gm + (size_t)li * HH;
    const float* g1   = l1g + (size_t)li * DDIM;
    const float* be1  = l1b + (size_t)li * DDIM;
    const float* g2   = l2g + (size_t)li * DDIM;
    const float* be2  = l2b + (size_t)li * DDIM;
    const float* W1_l = W1 + (size_t)li * DDIM * DFFN;
    const float* b1_l = b1 + (size_t)li * DFFN;
    const float* W2_l = W2 + (size_t)li * DFFN * DDIM;
    const float* b2_l = b2 + (size_t)li * DDIM;

    // qk projection (q == k: same input, same weights)
    gemm(query,  Wk_l, bk_l, R0, MR, DDIM, DDIM, DDIM, DDIM, 0, 0);
    // v projection
    gemm(values, Wv_l, bv_l, R1, MR, DDIM, DDIM, DDIM, DDIM, 0, 0);
    // attention (writes in-place over v buffer R1)
    attn_kernel<<<BB * HH, 512, 0, stream>>>(R0, R1, gm_l, R1, excl, zp);
    // output projection
    gemm(R1, Wo_l, bo_l, R2, MR, DDIM, DDIM, DDIM, DDIM, 0, 0);
    // x1 = LN(query + ao)
    float* x1 = pos ? R0 : outp;
    ln_kernel<<<MR / 4, 256, 0, stream>>>(query, R2, g1, be1, x1);
    if (pos) {
      // FFN chunked over DFF (4 chunks of 512) to bound workspace
      for (int c = 0; c < 4; ++c) {
        gemm(x1, W1_l + (size_t)c * 512, b1_l + (size_t)c * 512, R1,
             MR, 512, DDIM, DFFN, 512, 1, 0);
        gemm(R1, W2_l + (size_t)c * 512 * DDIM, (c == 0) ? b2_l : nullptr, R2,
             MR, DDIM, 512, DDIM, DDIM, 0, (c > 0) ? 1 : 0);
      }
      ln_kernel<<<MR / 4, 256, 0, stream>>>(x1, R2, g2, be2, outp);
    }
  };

  // blocks_1: self-attn on qa, mask incl, FFN
  layer(0, qa, qa, 0, 0, 1, Y1);
  // blocks_2 layer 1: self-attn on q, mask incl, no FFN
  layer(1, qe, qe, 0, 0, 0, X1);
  // blocks_2 layer 2: cross-attn (values = y1), strict mask, zero_pad, FFN
  layer(2, X1, Y1, 1, 1, 1, (float*)d_out);
}

// Round 2
// 5762.035 us; speedup vs baseline: 1.6362x; 1.6362x over previous
//
#include <hip/hip_runtime.h>

#define BB   32
#define SS   512
#define DDIM 512
#define HH   8
#define DKK  64
#define DFFN 2048
#define MR   (BB*SS)   // 16384 rows

// ---------- bf16 helpers ----------
__device__ __forceinline__ unsigned int packbf2(float x, float y) {
  unsigned int ux = __float_as_uint(x);
  unsigned int uy = __float_as_uint(y);
  unsigned int hx = (ux + 0x7FFFu + ((ux >> 16) & 1u)) >> 16;
  unsigned int hy = (uy + 0x7FFFu + ((uy >> 16) & 1u)) >> 16;
  return hx | (hy << 16);
}
__device__ __forceinline__ float bflo(unsigned int u) { return __uint_as_float(u << 16); }
__device__ __forceinline__ float bfhi(unsigned int u) { return __uint_as_float(u & 0xFFFF0000u); }

// ---------- tiled f32 GEMM: C[M,N] = A[M,K] @ B[K,N] (+bias) (+accum) (+relu) ----------
__global__ __launch_bounds__(256) void gemm_f32(
    const float* __restrict__ A, const float* __restrict__ Bm,
    const float* __restrict__ bias, float* __restrict__ C,
    int M, int N, int K, int ldb, int ldc, int relu, int accum)
{
  __shared__ float As[32][68];  // k-major: As[kk][r]
  __shared__ float Bs[32][68];  // k-major: Bs[kk][c]
  const int t  = threadIdx.x;
  const int tx = t & 15, ty = t >> 4;
  const int row0 = blockIdx.y * 64, col0 = blockIdx.x * 64;
  float acc[4][4] = {{0.f}};

  for (int k0 = 0; k0 < K; k0 += 32) {
    #pragma unroll
    for (int l = 0; l < 2; ++l) {
      int idx = t + l * 256;
      int r   = idx >> 3;
      int c4  = idx & 7;
      float4 v = *(const float4*)(A + (size_t)(row0 + r) * K + k0 + c4 * 4);
      As[c4*4+0][r] = v.x; As[c4*4+1][r] = v.y;
      As[c4*4+2][r] = v.z; As[c4*4+3][r] = v.w;
    }
    #pragma unroll
    for (int l = 0; l < 2; ++l) {
      int idx = t + l * 256;
      int r   = idx >> 4;
      int c4  = idx & 15;
      float4 v = *(const float4*)(Bm + (size_t)(k0 + r) * ldb + col0 + c4 * 4);
      Bs[r][c4*4+0] = v.x; Bs[r][c4*4+1] = v.y;
      Bs[r][c4*4+2] = v.z; Bs[r][c4*4+3] = v.w;
    }
    __syncthreads();
    #pragma unroll
    for (int kk = 0; kk < 32; ++kk) {
      float4 a4 = *(const float4*)(&As[kk][ty * 4]);
      float4 b4 = *(const float4*)(&Bs[kk][tx * 4]);
      float ar[4] = {a4.x, a4.y, a4.z, a4.w};
      float bc[4] = {b4.x, b4.y, b4.z, b4.w};
      #pragma unroll
      for (int rr = 0; rr < 4; ++rr)
        #pragma unroll
        for (int cc = 0; cc < 4; ++cc)
          acc[rr][cc] = fmaf(ar[rr], bc[cc], acc[rr][cc]);
    }
    __syncthreads();
  }

  #pragma unroll
  for (int rr = 0; rr < 4; ++rr) {
    int r = row0 + ty * 4 + rr;
    #pragma unroll
    for (int cc = 0; cc < 4; ++cc) {
      int c = col0 + tx * 4 + cc;
      float v = acc[rr][cc];
      if (bias)  v += bias[c];
      if (accum) v += C[(size_t)r * ldc + c];
      if (relu)  v = fmaxf(v, 0.f);
      C[(size_t)r * ldc + c] = v;
    }
  }
}

// ---------- attention with distance-decay rescoring (wave-per-row) ----------
// qk used as BOTH q and k. out may alias vbuf (each block reads its slice at
// staging, writes only its own (b,h) column slice afterwards).
// mask_excl: 0 -> valid j<=i ; 1 -> valid j<i.  zero_pad: zero row i==0.
#define KPAD 34
__global__ __launch_bounds__(512) void attn_kernel(
    const float* __restrict__ qk, const float* __restrict__ vbuf,
    const float* __restrict__ gam, float* __restrict__ out,
    int mask_excl, int zero_pad)
{
  __shared__ unsigned int kS[SS][KPAD];  // packed bf16x2 along d
  __shared__ unsigned int vS[SS][KPAD];
  __shared__ float pw[8][SS];            // per-wave p2 buffer
  __shared__ float qsh[8][64];           // per-wave q row

  const int t    = threadIdx.x;
  const int lane = t & 63, wid = t >> 6;
  const int bh   = blockIdx.x;
  const int b    = bh >> 3, h = bh & 7;
  const size_t base = (size_t)b * SS * DDIM + (size_t)h * DKK;

  // gamma = -softplus(gam[h]) (stable)
  float g  = gam[h];
  float sp = (g > 0.f) ? (g + log1pf(__expf(-g))) : log1pf(__expf(g));
  const float gamma = -sp;

  // stage K and V (packed bf16 pairs), coalesced float2 global reads
  for (int it = 0; it < 32; ++it) {
    int idx = it * 512 + t;
    int j = idx >> 5, m = idx & 31;
    float2 kf = *(const float2*)(qk + base + (size_t)j * DDIM + 2 * m);
    kS[j][m] = packbf2(kf.x, kf.y);
    float2 vf = *(const float2*)(vbuf + base + (size_t)j * DDIM + 2 * m);
    vS[j][m] = packbf2(vf.x, vf.y);
  }
  __syncthreads();

  const int d    = lane;
  const int mIdx = d >> 1;
  const bool dhi = d & 1;

  for (int it = 0; it < 64; ++it) {
    const int i = it * 8 + wid;

    if (zero_pad && i == 0) {
      out[base + (size_t)i * DDIM + d] = 0.f;
      continue;
    }

    const int nvalid = mask_excl ? i : (i + 1);
    const int nc     = (nvalid + 63) >> 6;

    // q row -> registers (via per-wave LDS broadcast)
    qsh[wid][lane] = qk[base + (size_t)i * DDIM + lane] * 0.125f; // 1/sqrt(64)
    float qv[64];
    #pragma unroll
    for (int dd = 0; dd < 64; ++dd) qv[dd] = qsh[wid][dd];

    // scores per chunk: lane handles j = c*64 + lane
    float sc[8];
    float m1 = -3.0e38f;
    #pragma unroll
    for (int c = 0; c < 8; ++c) {
      if (c < nc) {
        const int j = c * 64 + lane;
        float s = 0.f;
        #pragma unroll
        for (int mm = 0; mm < 16; ++mm) {
          uint2 u2 = *(const uint2*)&kS[j][2 * mm];
          s = fmaf(qv[4*mm+0], bflo(u2.x), s);
          s = fmaf(qv[4*mm+1], bfhi(u2.x), s);
          s = fmaf(qv[4*mm+2], bflo(u2.y), s);
          s = fmaf(qv[4*mm+3], bfhi(u2.y), s);
        }
        sc[c] = s;
        m1 = fmaxf(m1, (j < nvalid) ? s : -3.0e38f);
      } else sc[c] = 0.f;
    }
    #pragma unroll
    for (int off = 32; off > 0; off >>= 1) m1 = fmaxf(m1, __shfl_xor(m1, off, 64));

    // softmax1
    float p1c[8];
    float s1 = 0.f;
    #pragma unroll
    for (int c = 0; c < 8; ++c) {
      if (c < nc) {
        const int j = c * 64 + lane;
        float e = (j < nvalid) ? __expf(sc[c] - m1) : 0.f;
        p1c[c] = e;
        s1 += e;
      } else p1c[c] = 0.f;
    }
    #pragma unroll
    for (int off = 32; off > 0; off >>= 1) s1 += __shfl_xor(s1, off, 64);
    const float inv1 = 1.f / s1;

    // inclusive cumsum over j (per-chunk wave scan + running base)
    float inclc[8];
    float basep = 0.f;
    #pragma unroll
    for (int c = 0; c < 8; ++c) {
      if (c < nc) {
        float x = p1c[c] * inv1;
        #pragma unroll
        for (int off = 1; off < 64; off <<= 1) {
          float n = __shfl_up(x, off, 64);
          if (lane >= off) x += n;
        }
        inclc[c] = basep + x;
        basep += __shfl(x, 63, 64);
      } else inclc[c] = 0.f;
    }
    const float total = basep;

    // distance decay + rescoring
    float m2 = -3.0e38f;
    float s2c[8];
    #pragma unroll
    for (int c = 0; c < 8; ++c) {
      if (c < nc) {
        const int j = c * 64 + lane;
        float rem  = fmaxf(total - inclc[c], 0.f);
        float pos  = fabsf((float)(i - j));
        float dist = sqrtf(rem * pos);
        float eff  = __expf(gamma * dist);
        eff = fminf(fmaxf(eff, 1e-5f), 1e5f);
        float s2 = (j < nvalid) ? sc[c] * eff : -3.0e38f;
        s2c[c] = s2;
        m2 = fmaxf(m2, s2);
      } else s2c[c] = -3.0e38f;
    }
    #pragma unroll
    for (int off = 32; off > 0; off >>= 1) m2 = fmaxf(m2, __shfl_xor(m2, off, 64));

    float s2sum = 0.f;
    #pragma unroll
    for (int c = 0; c < 8; ++c) {
      if (c < nc) {
        const int j = c * 64 + lane;
        float e = (j < nvalid) ? __expf(s2c[c] - m2) : 0.f;
        s2c[c] = e;
        s2sum += e;
      }
    }
    #pragma unroll
    for (int off = 32; off > 0; off >>= 1) s2sum += __shfl_xor(s2sum, off, 64);
    const float inv2 = 1.f / s2sum;

    #pragma unroll
    for (int c = 0; c < 8; ++c) {
      if (c < nc) pw[wid][c * 64 + lane] = s2c[c] * inv2;
    }

    // PV: lane = output dim d; p broadcast from per-wave LDS
    float acc = 0.f;
    #pragma unroll 4
    for (int j2 = 0; j2 < nvalid; ++j2) {
      float pj = pw[wid][j2];
      unsigned int u = vS[j2][mIdx];
      float vv = dhi ? bfhi(u) : bflo(u);
      acc = fmaf(pj, vv, acc);
    }
    out[base + (size_t)i * DDIM + d] = acc;
  }
}

// ---------- fused residual + LayerNorm ----------
__global__ __launch_bounds__(256) void ln_kernel(
    const float* __restrict__ a, const float* __restrict__ bsrc,
    const float* __restrict__ g, const float* __restrict__ be,
    float* __restrict__ out)
{
  const int lane = threadIdx.x & 63, w = threadIdx.x >> 6;
  const size_t row = (size_t)blockIdx.x * 4 + w;
  const float* pa = a    + row * DDIM;
  const float* pb = bsrc + row * DDIM;
  float v[8];
  float sum = 0.f;
  #pragma unroll
  for (int c = 0; c < 2; ++c) {
    float4 va = *(const float4*)(pa + c * 256 + lane * 4);
    float4 vb = *(const float4*)(pb + c * 256 + lane * 4);
    v[c*4+0] = va.x + vb.x; v[c*4+1] = va.y + vb.y;
    v[c*4+2] = va.z + vb.z; v[c*4+3] = va.w + vb.w;
    sum += v[c*4+0] + v[c*4+1] + v[c*4+2] + v[c*4+3];
  }
  #pragma unroll
  for (int off = 32; off > 0; off >>= 1) sum += __shfl_xor(sum, off, 64);
  const float mean = sum * (1.f / 512.f);
  float var = 0.f;
  #pragma unroll
  for (int k = 0; k < 8; ++k) { float dd = v[k] - mean; var = fmaf(dd, dd, var); }
  #pragma unroll
  for (int off = 32; off > 0; off >>= 1) var += __shfl_xor(var, off, 64);
  var *= (1.f / 512.f);
  const float inv = rsqrtf(var + 1e-5f);
  float* po = out + row * DDIM;
  #pragma unroll
  for (int c = 0; c < 2; ++c) {
    float4 gg = *(const float4*)(g  + c * 256 + lane * 4);
    float4 bb = *(const float4*)(be + c * 256 + lane * 4);
    float4 o;
    o.x = (v[c*4+0] - mean) * inv * gg.x + bb.x;
    o.y = (v[c*4+1] - mean) * inv * gg.y + bb.y;
    o.z = (v[c*4+2] - mean) * inv * gg.z + bb.z;
    o.w = (v[c*4+3] - mean) * inv * gg.w + bb.w;
    *(float4*)(po + c * 256 + lane * 4) = o;
  }
}

// ---------- orchestration ----------
extern "C" void kernel_launch(void* const* d_in, const int* in_sizes, int n_in,
                              void* d_out, int out_size, void* d_ws, size_t ws_size,
                              hipStream_t stream) {
  const float* qe  = (const float*)d_in[0];
  const float* qa  = (const float*)d_in[1];
  const float* Wk  = (const float*)d_in[2];
  const float* bk  = (const float*)d_in[3];
  const float* Wv  = (const float*)d_in[4];
  const float* bv  = (const float*)d_in[5];
  const float* Wo  = (const float*)d_in[6];
  const float* bo  = (const float*)d_in[7];
  const float* gm  = (const float*)d_in[8];
  const float* l1g = (const float*)d_in[9];
  const float* l1b = (const float*)d_in[10];
  const float* W1  = (const float*)d_in[11];
  const float* b1  = (const float*)d_in[12];
  const float* W2  = (const float*)d_in[13];
  const float* b2  = (const float*)d_in[14];
  const float* l2g = (const float*)d_in[15];
  const float* l2b = (const float*)d_in[16];

  float* ws = (float*)d_ws;
  const size_t RSZ = (size_t)MR * DDIM;  // 32MB
  float* R0 = ws;
  float* R1 = ws + RSZ;
  float* R2 = ws + 2 * RSZ;
  float* Y1 = ws + 3 * RSZ;
  float* X1 = ws + 4 * RSZ;

  auto gemm = [&](const float* A, const float* Bp, const float* bias, float* C,
                  int M, int N, int K, int ldb, int ldc, int relu, int accum) {
    dim3 grid(N / 64, M / 64);
    gemm_f32<<<grid, 256, 0, stream>>>(A, Bp, bias, C, M, N, K, ldb, ldc, relu, accum);
  };

  auto layer = [&](int li, const float* query, const float* values,
                   int excl, int zp, int pos, float* outp) {
    const float* Wk_l = Wk + (size_t)li * DDIM * DDIM;
    const float* bk_l = bk + (size_t)li * DDIM;
    const float* Wv_l = Wv + (size_t)li * DDIM * DDIM;
    const float* bv_l = bv + (size_t)li * DDIM;
    const float* Wo_l = Wo + (size_t)li * DDIM * DDIM;
    const float* bo_l = bo + (size_t)li * DDIM;
    const float* gm_l = gm + (size_t)li * HH;
    const float* g1   = l1g + (size_t)li * DDIM;
    const float* be1  = l1b + (size_t)li * DDIM;
    const float* g2   = l2g + (size_t)li * DDIM;
    const float* be2  = l2b + (size_t)li * DDIM;
    const float* W1_l = W1 + (size_t)li * DDIM * DFFN;
    const float* b1_l = b1 + (size_t)li * DFFN;
    const float* W2_l = W2 + (size_t)li * DFFN * DDIM;
    const float* b2_l = b2 + (size_t)li * DDIM;

    gemm(query,  Wk_l, bk_l, R0, MR, DDIM, DDIM, DDIM, DDIM, 0, 0);
    gemm(values, Wv_l, bv_l, R1, MR, DDIM, DDIM, DDIM, DDIM, 0, 0);
    attn_kernel<<<BB * HH, 512, 0, stream>>>(R0, R1, gm_l, R1, excl, zp);
    gemm(R1, Wo_l, bo_l, R2, MR, DDIM, DDIM, DDIM, DDIM, 0, 0);
    float* x1 = pos ? R0 : outp;
    ln_kernel<<<MR / 4, 256, 0, stream>>>(query, R2, g1, be1, x1);
    if (pos) {
      for (int c = 0; c < 4; ++c) {
        gemm(x1, W1_l + (size_t)c * 512, b1_l + (size_t)c * 512, R1,
             MR, 512, DDIM, DFFN, 512, 1, 0);
        gemm(R1, W2_l + (size_t)c * 512 * DDIM, (c == 0) ? b2_l : nullptr, R2,
             MR, DDIM, 512, DDIM, DDIM, 0, (c > 0) ? 1 : 0);
      }
      ln_kernel<<<MR / 4, 256, 0, stream>>>(x1, R2, g2, be2, outp);
    }
  };

  layer(0, qa, qa, 0, 0, 1, Y1);
  layer(1, qe, qe, 0, 0, 0, X1);
  layer(2, X1, Y1, 1, 1, 1, (float*)d_out);
}

// Round 3
// 3121.495 us; speedup vs baseline: 3.0202x; 1.8459x over previous
//
#include <hip/hip_runtime.h>

#define BB   32
#define SS   512
#define DDIM 512
#define HH   8
#define DFFN 2048
#define MR   (BB*SS)   // 16384 rows

typedef unsigned int  u32;
typedef unsigned short u16;
typedef __attribute__((ext_vector_type(8))) short bf16x8;
typedef __attribute__((ext_vector_type(4))) float f32x4;

// ---------- bf16 helpers ----------
__device__ __forceinline__ u32 packbf2(float x, float y) {
  u32 ux = __float_as_uint(x), uy = __float_as_uint(y);
  u32 hx = (ux + 0x7FFFu + ((ux >> 16) & 1u)) >> 16;
  u32 hy = (uy + 0x7FFFu + ((uy >> 16) & 1u)) >> 16;
  return hx | (hy << 16);
}
__device__ __forceinline__ u16 pack1bf(float x) {
  u32 u = __float_as_uint(x);
  return (u16)((u + 0x7FFFu + ((u >> 16) & 1u)) >> 16);
}
__device__ __forceinline__ float bflo(u32 u) { return __uint_as_float(u << 16); }
__device__ __forceinline__ float bfhi(u32 u) { return __uint_as_float(u & 0xFFFF0000u); }
__device__ __forceinline__ float bf1(u16 h)  { return __uint_as_float(((u32)h) << 16); }

// ---------- flat f32 -> bf16 pack ----------
__global__ __launch_bounds__(256) void pack_flat(const float* __restrict__ in,
                                                 u16* __restrict__ out) {
  size_t i = ((size_t)blockIdx.x * 256 + threadIdx.x) * 8;
  float4 a = *(const float4*)(in + i);
  float4 b = *(const float4*)(in + i + 4);
  uint4 o;
  o.x = packbf2(a.x, a.y); o.y = packbf2(a.z, a.w);
  o.z = packbf2(b.x, b.y); o.w = packbf2(b.z, b.w);
  *(uint4*)(out + i) = o;
}

// ---------- weight transpose-pack: f32 [K,N] -> bf16 [N,K], gridDim.z = layers ----------
__global__ __launch_bounds__(256) void pack_w_t(const float* __restrict__ in,
                                                u16* __restrict__ out, int K, int N) {
  __shared__ float tile[64][65];
  const int t  = threadIdx.x;
  const int n0 = blockIdx.x * 64, k0 = blockIdx.y * 64;
  in  += (size_t)blockIdx.z * K * N;
  out += (size_t)blockIdx.z * N * K;
  #pragma unroll
  for (int it = 0; it < 4; ++it) {
    int idx = it * 256 + t;
    int kk = idx >> 4, n4 = idx & 15;
    float4 v = *(const float4*)(in + (size_t)(k0 + kk) * N + n0 + n4 * 4);
    tile[kk][n4*4+0] = v.x; tile[kk][n4*4+1] = v.y;
    tile[kk][n4*4+2] = v.z; tile[kk][n4*4+3] = v.w;
  }
  __syncthreads();
  #pragma unroll
  for (int it = 0; it < 4; ++it) {
    int idx = it * 256 + t;
    int nn = idx >> 4, g = idx & 15;
    uint2 o;
    o.x = packbf2(tile[g*4+0][nn], tile[g*4+1][nn]);
    o.y = packbf2(tile[g*4+2][nn], tile[g*4+3][nn]);
    *(uint2*)(out + (size_t)(n0 + nn) * K + k0 + g * 4) = o;
  }
}

// ---------- bf16 MFMA GEMM: C[M,N] = A[M,K] @ B[K,N], Bt = B^T stored [N][K] ----------
// 128x128 tile, BK=32, 256 threads (4 waves, 2x2), 4x4 16x16x32 frags per wave.
__global__ __launch_bounds__(256) void gemm_bf16(
    const u16* __restrict__ A, int lda,
    const u16* __restrict__ Bt, int ldb,
    const float* __restrict__ bias,
    float* __restrict__ outF, u16* __restrict__ outB, int ldc,
    int M, int N, int K, int relu, int accum)
{
  __shared__ u16 sA[128 * 32];  // [row][k], row stride 32
  __shared__ u16 sB[128 * 32];  // [col][k]
  const int t    = threadIdx.x;
  const int lane = t & 63, wid = t >> 6;
  const int wr   = wid >> 1, wc = wid & 1;
  const int row0 = blockIdx.y * 128, col0 = blockIdx.x * 128;
  const int kg   = lane >> 4, rl = lane & 15;

  f32x4 acc[4][4] = {};

  for (int k0 = 0; k0 < K; k0 += 32) {
    #pragma unroll
    for (int it = 0; it < 2; ++it) {
      int idx = it * 256 + t;
      int r = idx >> 2, seg = idx & 3;
      const u16* gA = A  + (size_t)(row0 + r) * lda + k0 + seg * 8;
      const u16* gB = Bt + (size_t)(col0 + r) * ldb + k0 + seg * 8;
      __builtin_amdgcn_global_load_lds(
          (const __attribute__((address_space(1))) u32*)gA,
          (__attribute__((address_space(3))) u32*)(sA + (it * 256 + wid * 64) * 8),
          16, 0, 0);
      __builtin_amdgcn_global_load_lds(
          (const __attribute__((address_space(1))) u32*)gB,
          (__attribute__((address_space(3))) u32*)(sB + (it * 256 + wid * 64) * 8),
          16, 0, 0);
    }
    __syncthreads();
    bf16x8 af[4], bfr[4];
    #pragma unroll
    for (int m = 0; m < 4; ++m)
      af[m] = *(const bf16x8*)(sA + (wr * 64 + m * 16 + rl) * 32 + kg * 8);
    #pragma unroll
    for (int n = 0; n < 4; ++n)
      bfr[n] = *(const bf16x8*)(sB + (wc * 64 + n * 16 + rl) * 32 + kg * 8);
    #pragma unroll
    for (int m = 0; m < 4; ++m)
      #pragma unroll
      for (int n = 0; n < 4; ++n)
        acc[m][n] = __builtin_amdgcn_mfma_f32_16x16x32_bf16(af[m], bfr[n], acc[m][n], 0, 0, 0);
    __syncthreads();
  }

  #pragma unroll
  for (int m = 0; m < 4; ++m) {
    #pragma unroll
    for (int n = 0; n < 4; ++n) {
      const int col = col0 + wc * 64 + n * 16 + rl;
      const float bs = bias ? bias[col] : 0.f;
      #pragma unroll
      for (int q = 0; q < 4; ++q) {
        const int row = row0 + wr * 64 + m * 16 + kg * 4 + q;
        float v = acc[m][n][q] + bs;
        if (accum) v += outF[(size_t)row * ldc + col];
        if (relu)  v = fmaxf(v, 0.f);
        if (outF)  outF[(size_t)row * ldc + col] = v;
        if (outB)  outB[(size_t)row * ldc + col] = pack1bf(v);
      }
    }
  }
}

// ---------- attention with distance-decay rescoring (wave-per-row, bf16 I/O) ----------
#define KPAD 34
__global__ __launch_bounds__(512) void attn_kernel(
    const u16* __restrict__ qk, const u16* __restrict__ vbuf,
    const float* __restrict__ gam, u16* __restrict__ out,
    int mask_excl, int zero_pad)
{
  __shared__ u32 kS[SS][KPAD];
  __shared__ u32 vS[SS][KPAD];
  __shared__ float pw[8][SS];
  __shared__ float qsh[8][64];

  const int t    = threadIdx.x;
  const int lane = t & 63, wid = t >> 6;
  const int bh   = blockIdx.x;
  const int b    = bh >> 3, h = bh & 7;
  const size_t base = (size_t)b * SS * DDIM + (size_t)h * 64;

  float g  = gam[h];
  float sp = (g > 0.f) ? (g + log1pf(__expf(-g))) : log1pf(__expf(g));
  const float gamma = -sp;

  // stage K and V (already bf16-packed in global)
  for (int it = 0; it < 16; ++it) {
    int idx = it * 512 + t;
    int j = idx >> 4, mp = idx & 15;
    *(uint2*)&kS[j][2 * mp] = *(const uint2*)(qk   + base + (size_t)j * DDIM + 4 * mp);
    *(uint2*)&vS[j][2 * mp] = *(const uint2*)(vbuf + base + (size_t)j * DDIM + 4 * mp);
  }
  __syncthreads();

  const int d    = lane;
  const int mIdx = d >> 1;
  const bool dhi = d & 1;

  for (int it = 0; it < 64; ++it) {
    const int i = it * 8 + wid;

    if (zero_pad && i == 0) {
      out[base + (size_t)i * DDIM + d] = 0;
      continue;
    }

    const int nvalid = mask_excl ? i : (i + 1);
    const int nc     = (nvalid + 63) >> 6;

    qsh[wid][lane] = bf1(qk[base + (size_t)i * DDIM + lane]) * 0.125f;
    float qv[64];
    #pragma unroll
    for (int dd = 0; dd < 64; ++dd) qv[dd] = qsh[wid][dd];

    float sc[8];
    float m1 = -3.0e38f;
    #pragma unroll
    for (int c = 0; c < 8; ++c) {
      if (c < nc) {
        const int j = c * 64 + lane;
        float s = 0.f;
        #pragma unroll
        for (int mm = 0; mm < 16; ++mm) {
          uint2 u2 = *(const uint2*)&kS[j][2 * mm];
          s = fmaf(qv[4*mm+0], bflo(u2.x), s);
          s = fmaf(qv[4*mm+1], bfhi(u2.x), s);
          s = fmaf(qv[4*mm+2], bflo(u2.y), s);
          s = fmaf(qv[4*mm+3], bfhi(u2.y), s);
        }
        sc[c] = s;
        m1 = fmaxf(m1, (j < nvalid) ? s : -3.0e38f);
      } else sc[c] = 0.f;
    }
    #pragma unroll
    for (int off = 32; off > 0; off >>= 1) m1 = fmaxf(m1, __shfl_xor(m1, off, 64));

    float p1c[8];
    float s1 = 0.f;
    #pragma unroll
    for (int c = 0; c < 8; ++c) {
      if (c < nc) {
        const int j = c * 64 + lane;
        float e = (j < nvalid) ? __expf(sc[c] - m1) : 0.f;
        p1c[c] = e;
        s1 += e;
      } else p1c[c] = 0.f;
    }
    #pragma unroll
    for (int off = 32; off > 0; off >>= 1) s1 += __shfl_xor(s1, off, 64);
    const float inv1 = 1.f / s1;

    float inclc[8];
    float basep = 0.f;
    #pragma unroll
    for (int c = 0; c < 8; ++c) {
      if (c < nc) {
        float x = p1c[c] * inv1;
        #pragma unroll
        for (int off = 1; off < 64; off <<= 1) {
          float n = __shfl_up(x, off, 64);
          if (lane >= off) x += n;
        }
        inclc[c] = basep + x;
        basep += __shfl(x, 63, 64);
      } else inclc[c] = 0.f;
    }
    const float total = basep;

    float m2 = -3.0e38f;
    float s2c[8];
    #pragma unroll
    for (int c = 0; c < 8; ++c) {
      if (c < nc) {
        const int j = c * 64 + lane;
        float rem  = fmaxf(total - inclc[c], 0.f);
        float pos  = fabsf((float)(i - j));
        float dist = sqrtf(rem * pos);
        float eff  = __expf(gamma * dist);
        eff = fminf(fmaxf(eff, 1e-5f), 1e5f);
        float s2 = (j < nvalid) ? sc[c] * eff : -3.0e38f;
        s2c[c] = s2;
        m2 = fmaxf(m2, s2);
      } else s2c[c] = -3.0e38f;
    }
    #pragma unroll
    for (int off = 32; off > 0; off >>= 1) m2 = fmaxf(m2, __shfl_xor(m2, off, 64));

    float s2sum = 0.f;
    #pragma unroll
    for (int c = 0; c < 8; ++c) {
      if (c < nc) {
        const int j = c * 64 + lane;
        float e = (j < nvalid) ? __expf(s2c[c] - m2) : 0.f;
        s2c[c] = e;
        s2sum += e;
      }
    }
    #pragma unroll
    for (int off = 32; off > 0; off >>= 1) s2sum += __shfl_xor(s2sum, off, 64);
    const float inv2 = 1.f / s2sum;

    #pragma unroll
    for (int c = 0; c < 8; ++c) {
      if (c < nc) pw[wid][c * 64 + lane] = s2c[c] * inv2;
    }

    float acc = 0.f;
    #pragma unroll 4
    for (int j2 = 0; j2 < nvalid; ++j2) {
      float pj = pw[wid][j2];
      u32 u = vS[j2][mIdx];
      float vv = dhi ? bfhi(u) : bflo(u);
      acc = fmaf(pj, vv, acc);
    }
    out[base + (size_t)i * DDIM + d] = pack1bf(acc);
  }
}

// ---------- fused residual + LayerNorm (dual f32/bf16 out) ----------
__global__ __launch_bounds__(256) void ln_kernel(
    const float* __restrict__ a, const float* __restrict__ bsrc,
    const float* __restrict__ g, const float* __restrict__ be,
    float* __restrict__ outF, u16* __restrict__ outB)
{
  const int lane = threadIdx.x & 63, w = threadIdx.x >> 6;
  const size_t row = (size_t)blockIdx.x * 4 + w;
  const float* pa = a    + row * DDIM;
  const float* pb = bsrc + row * DDIM;
  float v[8];
  float sum = 0.f;
  #pragma unroll
  for (int c = 0; c < 2; ++c) {
    float4 va = *(const float4*)(pa + c * 256 + lane * 4);
    float4 vb = *(const float4*)(pb + c * 256 + lane * 4);
    v[c*4+0] = va.x + vb.x; v[c*4+1] = va.y + vb.y;
    v[c*4+2] = va.z + vb.z; v[c*4+3] = va.w + vb.w;
    sum += v[c*4+0] + v[c*4+1] + v[c*4+2] + v[c*4+3];
  }
  #pragma unroll
  for (int off = 32; off > 0; off >>= 1) sum += __shfl_xor(sum, off, 64);
  const float mean = sum * (1.f / 512.f);
  float var = 0.f;
  #pragma unroll
  for (int k = 0; k < 8; ++k) { float dd = v[k] - mean; var = fmaf(dd, dd, var); }
  #pragma unroll
  for (int off = 32; off > 0; off >>= 1) var += __shfl_xor(var, off, 64);
  var *= (1.f / 512.f);
  const float inv = rsqrtf(var + 1e-5f);
  #pragma unroll
  for (int c = 0; c < 2; ++c) {
    float4 gg = *(const float4*)(g  + c * 256 + lane * 4);
    float4 bb = *(const float4*)(be + c * 256 + lane * 4);
    float4 o;
    o.x = (v[c*4+0] - mean) * inv * gg.x + bb.x;
    o.y = (v[c*4+1] - mean) * inv * gg.y + bb.y;
    o.z = (v[c*4+2] - mean) * inv * gg.z + bb.z;
    o.w = (v[c*4+3] - mean) * inv * gg.w + bb.w;
    const size_t off4 = row * DDIM + c * 256 + lane * 4;
    if (outF) *(float4*)(outF + off4) = o;
    if (outB) {
      uint2 p;
      p.x = packbf2(o.x, o.y); p.y = packbf2(o.z, o.w);
      *(uint2*)(outB + off4) = p;
    }
  }
}

// ---------- orchestration ----------
extern "C" void kernel_launch(void* const* d_in, const int* in_sizes, int n_in,
                              void* d_out, int out_size, void* d_ws, size_t ws_size,
                              hipStream_t stream) {
  const float* qe  = (const float*)d_in[0];
  const float* qa  = (const float*)d_in[1];
  const float* Wk  = (const float*)d_in[2];
  const float* bk  = (const float*)d_in[3];
  const float* Wv  = (const float*)d_in[4];
  const float* bv  = (const float*)d_in[5];
  const float* Wo  = (const float*)d_in[6];
  const float* bo  = (const float*)d_in[7];
  const float* gm  = (const float*)d_in[8];
  const float* l1g = (const float*)d_in[9];
  const float* l1b = (const float*)d_in[10];
  const float* W1  = (const float*)d_in[11];
  const float* b1  = (const float*)d_in[12];
  const float* W2  = (const float*)d_in[13];
  const float* b2  = (const float*)d_in[14];
  const float* l2g = (const float*)d_in[15];
  const float* l2b = (const float*)d_in[16];

  char* ws = (char*)d_ws;
  u16* WT = (u16*)ws;                              // 17.3 MB packed weights
  u16* A0 = (u16*)(ws + ((size_t)18  << 20));      // 16 MB bf16 act slots
  u16* A1 = (u16*)(ws + ((size_t)34  << 20));
  u16* A2 = (u16*)(ws + ((size_t)50  << 20));
  u16* A3 = (u16*)(ws + ((size_t)66  << 20));
  float* F0 = (float*)(ws + ((size_t)82  << 20));  // 32 MB f32 slots
  float* F1 = (float*)(ws + ((size_t)114 << 20));

  u16* WkT = WT;                    // [L][512][512]
  u16* WvT = WT + (size_t)3 * 262144;
  u16* WoT = WT + (size_t)6 * 262144;
  u16* W1T = WT + (size_t)9 * 262144;              // [L][2048][512]
  u16* W2T = W1T + (size_t)3 * 1048576;            // [L][512][2048]

  // weight packs (all 3 layers per dispatch via grid.z)
  pack_w_t<<<dim3(8, 8, 3),  256, 0, stream>>>(Wk, WkT, 512, 512);
  pack_w_t<<<dim3(8, 8, 3),  256, 0, stream>>>(Wv, WvT, 512, 512);
  pack_w_t<<<dim3(8, 8, 3),  256, 0, stream>>>(Wo, WoT, 512, 512);
  pack_w_t<<<dim3(32, 8, 3), 256, 0, stream>>>(W1, W1T, 512, 2048);
  pack_w_t<<<dim3(8, 32, 3), 256, 0, stream>>>(W2, W2T, 2048, 512);
  pack_flat<<<4096, 256, 0, stream>>>(qa, A0);
  pack_flat<<<4096, 256, 0, stream>>>(qe, A1);

  auto gemm = [&](const u16* A, int lda, const u16* Bt, int ldb, const float* bias,
                  float* outF, u16* outB, int ldc, int M, int N, int K,
                  int relu, int accum) {
    gemm_bf16<<<dim3(N / 128, M / 128), 256, 0, stream>>>(
        A, lda, Bt, ldb, bias, outF, outB, ldc, M, N, K, relu, accum);
  };

  // one transformer layer.
  //  qbf: bf16 query (= key input), qf32: f32 query (residual), vbf: bf16 values
  //  ln1 -> (lnF f32, lnB bf16); if pos: FFN uses lnB, mid buffer midB, ln2 -> (y2F,y2B)
  auto layer = [&](int li, const u16* qbf, const float* qf32, const u16* vbf,
                   int excl, int zp, int pos,
                   float* lnF, u16* lnB, u16* midB, float* y2F, u16* y2B) {
    const float* bk_l = bk + (size_t)li * DDIM;
    const float* bv_l = bv + (size_t)li * DDIM;
    const float* bo_l = bo + (size_t)li * DDIM;
    const float* gm_l = gm + (size_t)li * HH;
    const float* g1   = l1g + (size_t)li * DDIM;
    const float* be1  = l1b + (size_t)li * DDIM;
    const float* g2   = l2g + (size_t)li * DDIM;
    const float* be2  = l2b + (size_t)li * DDIM;
    const float* b1_l = b1 + (size_t)li * DFFN;
    const float* b2_l = b2 + (size_t)li * DDIM;
    const u16* WkT_l = WkT + (size_t)li * 262144;
    const u16* WvT_l = WvT + (size_t)li * 262144;
    const u16* WoT_l = WoT + (size_t)li * 262144;
    const u16* W1T_l = W1T + (size_t)li * 1048576;
    const u16* W2T_l = W2T + (size_t)li * 1048576;

    gemm(qbf, 512, WkT_l, 512, bk_l, nullptr, A2, 512, MR, 512, 512, 0, 0);
    gemm(vbf, 512, WvT_l, 512, bv_l, nullptr, A3, 512, MR, 512, 512, 0, 0);
    attn_kernel<<<BB * HH, 512, 0, stream>>>(A2, A3, gm_l, A3, excl, zp);
    gemm(A3, 512, WoT_l, 512, bo_l, F0, nullptr, 512, MR, 512, 512, 0, 0);
    ln_kernel<<<MR / 4, 256, 0, stream>>>(qf32, F0, g1, be1, lnF, lnB);
    if (pos) {
      for (int c = 0; c < 4; ++c) {
        gemm(lnB, 512, W1T_l + (size_t)c * 512 * 512, 512, b1_l + c * 512,
             nullptr, midB, 512, MR, 512, 512, 1, 0);
        gemm(midB, 512, W2T_l + (size_t)c * 512, 2048, (c == 0) ? b2_l : nullptr,
             F0, nullptr, 512, MR, 512, 512, 0, (c > 0) ? 1 : 0);
      }
      ln_kernel<<<MR / 4, 256, 0, stream>>>(lnF, F0, g2, be2, y2F, y2B);
    }
  };

  // layer 0: self-attn on qa, incl mask, FFN -> y1 (bf16 in A0)
  layer(0, A0, qa, A0, 0, 0, 1, F1, A2, A3, nullptr, A0);
  // layer 1: self-attn on qe, incl mask, no FFN -> x1 (f32 F1, bf16 A1)
  layer(1, A1, qe, A1, 0, 0, 0, F1, A1, nullptr, nullptr, nullptr);
  // layer 2: cross-attn (q = x1, values = y1), strict mask, zero_pad, FFN -> d_out
  layer(2, A1, F1, A0, 1, 1, 1, F1, A1, A2, (float*)d_out, nullptr);
}

// Round 4
// 1351.275 us; speedup vs baseline: 6.9769x; 2.3100x over previous
//
#include <hip/hip_runtime.h>

#define BB   32
#define SS   512
#define DDIM 512
#define HH   8
#define DFFN 2048
#define MR   (BB*SS)   // 16384 rows

typedef unsigned int   u32;
typedef unsigned short u16;
typedef unsigned char  u8;
typedef __attribute__((ext_vector_type(8))) short bf16x8;
typedef __attribute__((ext_vector_type(4))) float f32x4;

// ---------- bf16 helpers ----------
__device__ __forceinline__ u32 packbf2(float x, float y) {
  u32 ux = __float_as_uint(x), uy = __float_as_uint(y);
  u32 hx = (ux + 0x7FFFu + ((ux >> 16) & 1u)) >> 16;
  u32 hy = (uy + 0x7FFFu + ((uy >> 16) & 1u)) >> 16;
  return hx | (hy << 16);
}
__device__ __forceinline__ u16 pack1bf(float x) {
  u32 u = __float_as_uint(x);
  return (u16)((u + 0x7FFFu + ((u >> 16) & 1u)) >> 16);
}
__device__ __forceinline__ float bflo(u32 u) { return __uint_as_float(u << 16); }
__device__ __forceinline__ float bfhi(u32 u) { return __uint_as_float(u & 0xFFFF0000u); }
__device__ __forceinline__ float bf1(u16 h)  { return __uint_as_float(((u32)h) << 16); }

__device__ __forceinline__ float redsum2(float v) {
  v += __shfl_xor(v, 16, 64);
  v += __shfl_xor(v, 32, 64);
  return v;
}
__device__ __forceinline__ float redmax2(float v) {
  v = fmaxf(v, __shfl_xor(v, 16, 64));
  v = fmaxf(v, __shfl_xor(v, 32, 64));
  return v;
}

// ---------- flat f32 -> bf16 pack ----------
__global__ __launch_bounds__(256) void pack_flat(const float* __restrict__ in,
                                                 u16* __restrict__ out) {
  size_t i = ((size_t)blockIdx.x * 256 + threadIdx.x) * 8;
  float4 a = *(const float4*)(in + i);
  float4 b = *(const float4*)(in + i + 4);
  uint4 o;
  o.x = packbf2(a.x, a.y); o.y = packbf2(a.z, a.w);
  o.z = packbf2(b.x, b.y); o.w = packbf2(b.z, b.w);
  *(uint4*)(out + i) = o;
}

// ---------- weight transpose-pack: f32 [K,N] -> bf16 [N,K], gridDim.z = layers ----------
__global__ __launch_bounds__(256) void pack_w_t(const float* __restrict__ in,
                                                u16* __restrict__ out, int K, int N) {
  __shared__ float tile[64][65];
  const int t  = threadIdx.x;
  const int n0 = blockIdx.x * 64, k0 = blockIdx.y * 64;
  in  += (size_t)blockIdx.z * K * N;
  out += (size_t)blockIdx.z * N * K;
  #pragma unroll
  for (int it = 0; it < 4; ++it) {
    int idx = it * 256 + t;
    int kk = idx >> 4, n4 = idx & 15;
    float4 v = *(const float4*)(in + (size_t)(k0 + kk) * N + n0 + n4 * 4);
    tile[kk][n4*4+0] = v.x; tile[kk][n4*4+1] = v.y;
    tile[kk][n4*4+2] = v.z; tile[kk][n4*4+3] = v.w;
  }
  __syncthreads();
  #pragma unroll
  for (int it = 0; it < 4; ++it) {
    int idx = it * 256 + t;
    int nn = idx >> 4, g = idx & 15;
    uint2 o;
    o.x = packbf2(tile[g*4+0][nn], tile[g*4+1][nn]);
    o.y = packbf2(tile[g*4+2][nn], tile[g*4+3][nn]);
    *(uint2*)(out + (size_t)(n0 + nn) * K + k0 + g * 4) = o;
  }
}

// ---------- bf16 MFMA GEMM: C[M,N] = A[M,K] @ B[K,N], Bt = B^T stored [N][K] ----------
__global__ __launch_bounds__(256) void gemm_bf16(
    const u16* __restrict__ A, int lda,
    const u16* __restrict__ Bt, int ldb,
    const float* __restrict__ bias,
    float* __restrict__ outF, u16* __restrict__ outB, int ldc,
    int M, int N, int K, int relu, int accum)
{
  __shared__ u16 sA[128 * 32];  // [row][k], row stride 32
  __shared__ u16 sB[128 * 32];  // [col][k]
  const int t    = threadIdx.x;
  const int lane = t & 63, wid = t >> 6;
  const int wr   = wid >> 1, wc = wid & 1;
  const int row0 = blockIdx.y * 128, col0 = blockIdx.x * 128;
  const int kg   = lane >> 4, rl = lane & 15;

  f32x4 acc[4][4] = {};

  for (int k0 = 0; k0 < K; k0 += 32) {
    #pragma unroll
    for (int it = 0; it < 2; ++it) {
      int idx = it * 256 + t;
      int r = idx >> 2, seg = idx & 3;
      const u16* gA = A  + (size_t)(row0 + r) * lda + k0 + seg * 8;
      const u16* gB = Bt + (size_t)(col0 + r) * ldb + k0 + seg * 8;
      __builtin_amdgcn_global_load_lds(
          (const __attribute__((address_space(1))) u32*)gA,
          (__attribute__((address_space(3))) u32*)(sA + (it * 256 + wid * 64) * 8),
          16, 0, 0);
      __builtin_amdgcn_global_load_lds(
          (const __attribute__((address_space(1))) u32*)gB,
          (__attribute__((address_space(3))) u32*)(sB + (it * 256 + wid * 64) * 8),
          16, 0, 0);
    }
    __syncthreads();
    bf16x8 af[4], bfr[4];
    #pragma unroll
    for (int m = 0; m < 4; ++m)
      af[m] = *(const bf16x8*)(sA + (wr * 64 + m * 16 + rl) * 32 + kg * 8);
    #pragma unroll
    for (int n = 0; n < 4; ++n)
      bfr[n] = *(const bf16x8*)(sB + (wc * 64 + n * 16 + rl) * 32 + kg * 8);
    #pragma unroll
    for (int m = 0; m < 4; ++m)
      #pragma unroll
      for (int n = 0; n < 4; ++n)
        acc[m][n] = __builtin_amdgcn_mfma_f32_16x16x32_bf16(af[m], bfr[n], acc[m][n], 0, 0, 0);
    __syncthreads();
  }

  #pragma unroll
  for (int m = 0; m < 4; ++m) {
    #pragma unroll
    for (int n = 0; n < 4; ++n) {
      const int col = col0 + wc * 64 + n * 16 + rl;
      const float bs = bias ? bias[col] : 0.f;
      #pragma unroll
      for (int q = 0; q < 4; ++q) {
        const int row = row0 + wr * 64 + m * 16 + kg * 4 + q;
        float v = acc[m][n][q] + bs;
        if (accum) v += outF[(size_t)row * ldc + col];
        if (relu)  v = fmaxf(v, 0.f);
        if (outF)  outF[(size_t)row * ldc + col] = v;
        if (outB)  outB[(size_t)row * ldc + col] = pack1bf(v);
      }
    }
  }
}

// ---------- MFMA attention with distance-decay rescoring ----------
// Block = (b,h), 512 threads (8 waves). Each wave owns 4 row-tiles of 16 q-rows
// {w, 15-w, 16+w, 31-w} (balanced causal work). Swapped QK^T (mfma(K,Q) -> S^T)
// keeps all softmax/cumsum math nearly lane-local. out may alias vbuf.
__global__ __launch_bounds__(512, 2) void attn_mfma(
    const u16* __restrict__ qk, const u16* __restrict__ vbuf,
    const float* __restrict__ gam, u16* __restrict__ out,
    int mask_excl, int zero_pad)
{
  __shared__ __align__(16) u8 kSb[65536];  // K/Q rows [512][64] bf16, byte ^= (row&7)<<4
  __shared__ __align__(16) u8 vTb[65536];  // V^T [64 d][512 k] bf16, byte ^= (d&7)<<4
  __shared__ __align__(16) u8 pChb[8192];  // per-wave 1KB P chunk buffers

  const int t    = threadIdx.x;
  const int lane = t & 63, wid = t >> 6;
  const int ql   = lane & 15, g = lane >> 4;
  const int bh   = blockIdx.x, b = bh >> 3, h = bh & 7;
  const size_t base = (size_t)b * SS * DDIM + (size_t)h * 64;

  float gv = gam[h];
  float sp = (gv > 0.f) ? (gv + log1pf(__expf(-gv))) : log1pf(__expf(gv));
  const float gamma = -sp;

  // ---- stage K/Q ----
  for (int it = 0; it < 8; ++it) {
    int idx = it * 512 + t;
    int j = idx >> 3, u = idx & 7;
    uint4 w = *(const uint4*)(qk + base + (size_t)j * DDIM + u * 8);
    *(uint4*)(kSb + ((j * 128 + u * 16) ^ ((j & 7) << 4))) = w;
  }
  // ---- stage V transposed ----
  for (int it = 0; it < 8; ++it) {
    int idx = it * 512 + t;
    int j = idx >> 3, u = idx & 7;
    union { uint4 v4; u16 s[8]; } uu;
    uu.v4 = *(const uint4*)(vbuf + base + (size_t)j * DDIM + u * 8);
    #pragma unroll
    for (int dd = 0; dd < 8; ++dd) {
      int d = u * 8 + dd;
      *(u16*)(vTb + ((d * 1024 + 2 * j) ^ ((d & 7) << 4))) = uu.s[dd];
    }
  }
  __syncthreads();

  // diagonal-tile validity per (g, reg): k_local = 4g+reg vs q_local = ql
  bool vm[4];
  #pragma unroll
  for (int rg = 0; rg < 4; ++rg) {
    int kl = 4 * g + rg;
    vm[rg] = mask_excl ? (kl < ql) : (kl <= ql);
  }

  u8* pB = pChb + wid * 1024;
  const int swp = (ql & 3) << 4;

  #pragma unroll
  for (int ri = 0; ri < 4; ++ri) {
    int r0_ = (ri == 0) ? wid : (ri == 1) ? (15 - wid) : (ri == 2) ? (16 + wid) : (31 - wid);
    const int rs = __builtin_amdgcn_readfirstlane(r0_);
    const int i0 = rs * 16;

    // Q B-frags (row = i0+ql, d-slots g / 4+g)
    const int qrow = i0 + ql;
    const int qsw  = (qrow & 7) << 4;
    bf16x8 qf0 = *(const bf16x8*)(kSb + ((qrow * 128      + g * 16) ^ qsw));
    bf16x8 qf1 = *(const bf16x8*)(kSb + ((qrow * 128 + 64 + g * 16) ^ qsw));

    // ---- pass 1: scores S^T (raw dot), track m1 ----
    f32x4 sc[32];
    float m1 = -3.0e38f;
    #pragma unroll
    for (int kt = 0; kt < 32; ++kt) {
      if (kt <= rs) {
        const int krow = kt * 16 + ql;
        const int ksw  = (krow & 7) << 4;
        bf16x8 ka0 = *(const bf16x8*)(kSb + ((krow * 128      + g * 16) ^ ksw));
        bf16x8 ka1 = *(const bf16x8*)(kSb + ((krow * 128 + 64 + g * 16) ^ ksw));
        f32x4 d = {};
        d = __builtin_amdgcn_mfma_f32_16x16x32_bf16(ka0, qf0, d, 0, 0, 0);
        d = __builtin_amdgcn_mfma_f32_16x16x32_bf16(ka1, qf1, d, 0, 0, 0);
        sc[kt] = d;
        if (kt < rs) {
          #pragma unroll
          for (int rg = 0; rg < 4; ++rg) m1 = fmaxf(m1, d[rg]);
        } else {
          #pragma unroll
          for (int rg = 0; rg < 4; ++rg) m1 = fmaxf(m1, vm[rg] ? d[rg] : -3.0e38f);
        }
      }
    }
    m1 = redmax2(m1);
    const float m1s = 0.125f * m1;

    // ---- pass 2a: S1 ----
    float S1l = 0.f;
    #pragma unroll
    for (int kt = 0; kt < 32; ++kt) {
      if (kt <= rs) {
        const bool dg = (kt == rs);
        #pragma unroll
        for (int rg = 0; rg < 4; ++rg) {
          float e = __expf(0.125f * sc[kt][rg] - m1s);
          if (dg && !vm[rg]) e = 0.f;
          S1l += e;
        }
      }
    }
    const float S1   = redsum2(S1l);
    const float inv1 = 1.f / S1;   // inf only for fully-masked q=0 row (excl); contained

    // ---- pass 2b: cumsum + distance decay + rescoring ----
    float cbase = 0.f, m2 = -3.0e38f;
    const float qlf = (float)(i0 + ql);
    #pragma unroll
    for (int kt = 0; kt < 32; ++kt) {
      if (kt <= rs) {
        const bool dg = (kt == rs);
        float e0 = __expf(0.125f * sc[kt][0] - m1s);
        float e1 = __expf(0.125f * sc[kt][1] - m1s);
        float e2 = __expf(0.125f * sc[kt][2] - m1s);
        float e3 = __expf(0.125f * sc[kt][3] - m1s);
        if (dg) {
          if (!vm[0]) e0 = 0.f;
          if (!vm[1]) e1 = 0.f;
          if (!vm[2]) e2 = 0.f;
          if (!vm[3]) e3 = 0.f;
        }
        float p0 = e0, p1 = p0 + e1, p2s = p1 + e2, L = p2s + e3;
        float a16 = __shfl_up(L, 16, 64);
        float a32 = __shfl_up(L, 32, 64);
        float a48 = __shfl_up(L, 48, 64);
        float gp = (g >= 1 ? a16 : 0.f) + (g >= 2 ? a32 : 0.f) + (g >= 3 ? a48 : 0.f);
        float tt = __shfl(gp + L, ql + 48, 64);
        const float pbase = cbase + gp;
        const float pf = qlf - (float)(kt * 16 + 4 * g);
        float ipr[4] = {p0, p1, p2s, L};
        #pragma unroll
        for (int rg = 0; rg < 4; ++rg) {
          float rem  = fmaxf((S1 - (pbase + ipr[rg])) * inv1, 0.f);
          float pos  = pf - (float)rg;
          float dist = sqrtf(fmaxf(rem * pos, 0.f));
          float eff  = fmaxf(__expf(gamma * dist), 1e-5f);  // eff <= 1 since gamma < 0
          float s2 = 0.125f * sc[kt][rg] * eff;
          if (dg && !vm[rg]) s2 = -3.0e38f;
          sc[kt][rg] = s2;
          m2 = fmaxf(m2, s2);
        }
        cbase += tt;
      }
    }
    m2 = redmax2(m2);

    // ---- pass 3: e2, S2 ----
    float S2l = 0.f;
    #pragma unroll
    for (int kt = 0; kt < 32; ++kt) {
      if (kt <= rs) {
        #pragma unroll
        for (int rg = 0; rg < 4; ++rg) {
          float e = __expf(sc[kt][rg] - m2);
          sc[kt][rg] = e;
          S2l += e;
        }
      }
    }
    const float S2   = redsum2(S2l);
    const float inv2 = 1.f / fmaxf(S2, 1e-30f);

    // ---- pass 4: PV via MFMA, P through per-wave LDS chunk buffer ----
    f32x4 oacc[4] = {};
    #pragma unroll
    for (int c = 0; c < 16; ++c) {
      if (2 * c <= rs) {
        const bool t2v = (2 * c + 1 <= rs);
        u32 w0 = packbf2(sc[2*c][0] * inv2, sc[2*c][1] * inv2);
        u32 w1 = packbf2(sc[2*c][2] * inv2, sc[2*c][3] * inv2);
        u32 w2 = t2v ? packbf2(sc[2*c+1][0] * inv2, sc[2*c+1][1] * inv2) : 0u;
        u32 w3 = t2v ? packbf2(sc[2*c+1][2] * inv2, sc[2*c+1][3] * inv2) : 0u;
        *(u32*)(pB + ((ql * 64 +      8 * g    ) ^ swp)) = w0;
        *(u32*)(pB + ((ql * 64 +      8 * g + 4) ^ swp)) = w1;
        *(u32*)(pB + ((ql * 64 + 32 + 8 * g    ) ^ swp)) = w2;
        *(u32*)(pB + ((ql * 64 + 32 + 8 * g + 4) ^ swp)) = w3;
        bf16x8 pa = *(const bf16x8*)(pB + ((ql * 64 + 16 * g) ^ swp));
        #pragma unroll
        for (int n = 0; n < 4; ++n) {
          const int d = n * 16 + ql;
          bf16x8 vb = *(const bf16x8*)(vTb + ((d * 1024 + 64 * c + 16 * g) ^ ((d & 7) << 4)));
          oacc[n] = __builtin_amdgcn_mfma_f32_16x16x32_bf16(pa, vb, oacc[n], 0, 0, 0);
        }
      }
    }

    // ---- store O tile: q_out = i0 + 4g + reg, d = n*16 + ql ----
    #pragma unroll
    for (int n = 0; n < 4; ++n) {
      #pragma unroll
      for (int rg = 0; rg < 4; ++rg) {
        const int qo = i0 + 4 * g + rg;
        float val = oacc[n][rg];
        if (zero_pad && qo == 0) val = 0.f;
        out[base + (size_t)qo * DDIM + n * 16 + ql] = pack1bf(val);
      }
    }
  }
}

// ---------- fused residual + LayerNorm (dual f32/bf16 out) ----------
__global__ __launch_bounds__(256) void ln_kernel(
    const float* __restrict__ a, const float* __restrict__ bsrc,
    const float* __restrict__ g, const float* __restrict__ be,
    float* __restrict__ outF, u16* __restrict__ outB)
{
  const int lane = threadIdx.x & 63, w = threadIdx.x >> 6;
  const size_t row = (size_t)blockIdx.x * 4 + w;
  const float* pa = a    + row * DDIM;
  const float* pb = bsrc + row * DDIM;
  float v[8];
  float sum = 0.f;
  #pragma unroll
  for (int c = 0; c < 2; ++c) {
    float4 va = *(const float4*)(pa + c * 256 + lane * 4);
    float4 vb = *(const float4*)(pb + c * 256 + lane * 4);
    v[c*4+0] = va.x + vb.x; v[c*4+1] = va.y + vb.y;
    v[c*4+2] = va.z + vb.z; v[c*4+3] = va.w + vb.w;
    sum += v[c*4+0] + v[c*4+1] + v[c*4+2] + v[c*4+3];
  }
  #pragma unroll
  for (int off = 32; off > 0; off >>= 1) sum += __shfl_xor(sum, off, 64);
  const float mean = sum * (1.f / 512.f);
  float var = 0.f;
  #pragma unroll
  for (int k = 0; k < 8; ++k) { float dd = v[k] - mean; var = fmaf(dd, dd, var); }
  #pragma unroll
  for (int off = 32; off > 0; off >>= 1) var += __shfl_xor(var, off, 64);
  var *= (1.f / 512.f);
  const float inv = rsqrtf(var + 1e-5f);
  #pragma unroll
  for (int c = 0; c < 2; ++c) {
    float4 gg = *(const float4*)(g  + c * 256 + lane * 4);
    float4 bb = *(const float4*)(be + c * 256 + lane * 4);
    float4 o;
    o.x = (v[c*4+0] - mean) * inv * gg.x + bb.x;
    o.y = (v[c*4+1] - mean) * inv * gg.y + bb.y;
    o.z = (v[c*4+2] - mean) * inv * gg.z + bb.z;
    o.w = (v[c*4+3] - mean) * inv * gg.w + bb.w;
    const size_t off4 = row * DDIM + c * 256 + lane * 4;
    if (outF) *(float4*)(outF + off4) = o;
    if (outB) {
      uint2 p;
      p.x = packbf2(o.x, o.y); p.y = packbf2(o.z, o.w);
      *(uint2*)(outB + off4) = p;
    }
  }
}

// ---------- orchestration ----------
extern "C" void kernel_launch(void* const* d_in, const int* in_sizes, int n_in,
                              void* d_out, int out_size, void* d_ws, size_t ws_size,
                              hipStream_t stream) {
  const float* qe  = (const float*)d_in[0];
  const float* qa  = (const float*)d_in[1];
  const float* Wk  = (const float*)d_in[2];
  const float* bk  = (const float*)d_in[3];
  const float* Wv  = (const float*)d_in[4];
  const float* bv  = (const float*)d_in[5];
  const float* Wo  = (const float*)d_in[6];
  const float* bo  = (const float*)d_in[7];
  const float* gm  = (const float*)d_in[8];
  const float* l1g = (const float*)d_in[9];
  const float* l1b = (const float*)d_in[10];
  const float* W1  = (const float*)d_in[11];
  const float* b1  = (const float*)d_in[12];
  const float* W2  = (const float*)d_in[13];
  const float* b2  = (const float*)d_in[14];
  const float* l2g = (const float*)d_in[15];
  const float* l2b = (const float*)d_in[16];

  char* ws = (char*)d_ws;
  u16* WT = (u16*)ws;                              // 17.3 MB packed weights
  u16* A0 = (u16*)(ws + ((size_t)18  << 20));      // 16 MB bf16 act slots
  u16* A1 = (u16*)(ws + ((size_t)34  << 20));
  u16* A2 = (u16*)(ws + ((size_t)50  << 20));
  u16* A3 = (u16*)(ws + ((size_t)66  << 20));
  float* F0 = (float*)(ws + ((size_t)82  << 20));  // 32 MB f32 slots
  float* F1 = (float*)(ws + ((size_t)114 << 20));

  u16* WkT = WT;                    // [L][512][512]
  u16* WvT = WT + (size_t)3 * 262144;
  u16* WoT = WT + (size_t)6 * 262144;
  u16* W1T = WT + (size_t)9 * 262144;              // [L][2048][512]
  u16* W2T = W1T + (size_t)3 * 1048576;            // [L][512][2048]

  pack_w_t<<<dim3(8, 8, 3),  256, 0, stream>>>(Wk, WkT, 512, 512);
  pack_w_t<<<dim3(8, 8, 3),  256, 0, stream>>>(Wv, WvT, 512, 512);
  pack_w_t<<<dim3(8, 8, 3),  256, 0, stream>>>(Wo, WoT, 512, 512);
  pack_w_t<<<dim3(32, 8, 3), 256, 0, stream>>>(W1, W1T, 512, 2048);
  pack_w_t<<<dim3(8, 32, 3), 256, 0, stream>>>(W2, W2T, 2048, 512);
  pack_flat<<<4096, 256, 0, stream>>>(qa, A0);
  pack_flat<<<4096, 256, 0, stream>>>(qe, A1);

  auto gemm = [&](const u16* A, int lda, const u16* Bt, int ldb, const float* bias,
                  float* outF, u16* outB, int ldc, int M, int N, int K,
                  int relu, int accum) {
    gemm_bf16<<<dim3(N / 128, M / 128), 256, 0, stream>>>(
        A, lda, Bt, ldb, bias, outF, outB, ldc, M, N, K, relu, accum);
  };

  auto layer = [&](int li, const u16* qbf, const float* qf32, const u16* vbf,
                   int excl, int zp, int pos,
                   float* lnF, u16* lnB, u16* midB, float* y2F, u16* y2B) {
    const float* bk_l = bk + (size_t)li * DDIM;
    const float* bv_l = bv + (size_t)li * DDIM;
    const float* bo_l = bo + (size_t)li * DDIM;
    const float* gm_l = gm + (size_t)li * HH;
    const float* g1   = l1g + (size_t)li * DDIM;
    const float* be1  = l1b + (size_t)li * DDIM;
    const float* g2   = l2g + (size_t)li * DDIM;
    const float* be2  = l2b + (size_t)li * DDIM;
    const float* b1_l = b1 + (size_t)li * DFFN;
    const float* b2_l = b2 + (size_t)li * DDIM;
    const u16* WkT_l = WkT + (size_t)li * 262144;
    const u16* WvT_l = WvT + (size_t)li * 262144;
    const u16* WoT_l = WoT + (size_t)li * 262144;
    const u16* W1T_l = W1T + (size_t)li * 1048576;
    const u16* W2T_l = W2T + (size_t)li * 1048576;

    gemm(qbf, 512, WkT_l, 512, bk_l, nullptr, A2, 512, MR, 512, 512, 0, 0);
    gemm(vbf, 512, WvT_l, 512, bv_l, nullptr, A3, 512, MR, 512, 512, 0, 0);
    attn_mfma<<<BB * HH, 512, 0, stream>>>(A2, A3, gm_l, A3, excl, zp);
    gemm(A3, 512, WoT_l, 512, bo_l, F0, nullptr, 512, MR, 512, 512, 0, 0);
    ln_kernel<<<MR / 4, 256, 0, stream>>>(qf32, F0, g1, be1, lnF, lnB);
    if (pos) {
      for (int c = 0; c < 4; ++c) {
        gemm(lnB, 512, W1T_l + (size_t)c * 512 * 512, 512, b1_l + c * 512,
             nullptr, midB, 512, MR, 512, 512, 1, 0);
        gemm(midB, 512, W2T_l + (size_t)c * 512, 2048, (c == 0) ? b2_l : nullptr,
             F0, nullptr, 512, MR, 512, 512, 0, (c > 0) ? 1 : 0);
      }
      ln_kernel<<<MR / 4, 256, 0, stream>>>(lnF, F0, g2, be2, y2F, y2B);
    }
  };

  layer(0, A0, qa, A0, 0, 0, 1, F1, A2, A3, nullptr, A0);
  layer(1, A1, qe, A1, 0, 0, 0, F1, A1, nullptr, nullptr, nullptr);
  layer(2, A1, F1, A0, 1, 1, 1, F1, A1, A2, (float*)d_out, nullptr);
}

// Round 5
// 1137.870 us; speedup vs baseline: 8.2854x; 1.1875x over previous
//
#include <hip/hip_runtime.h>

#define BB   32
#define SS   512
#define DDIM 512
#define HH   8
#define DFFN 2048
#define MR   (BB*SS)   // 16384 rows

typedef unsigned int   u32;
typedef unsigned short u16;
typedef unsigned char  u8;
typedef __attribute__((ext_vector_type(8))) short bf16x8;
typedef __attribute__((ext_vector_type(4))) float f32x4;

// ---------- bf16 helpers ----------
__device__ __forceinline__ u32 packbf2(float x, float y) {
  u32 ux = __float_as_uint(x), uy = __float_as_uint(y);
  u32 hx = (ux + 0x7FFFu + ((ux >> 16) & 1u)) >> 16;
  u32 hy = (uy + 0x7FFFu + ((uy >> 16) & 1u)) >> 16;
  return hx | (hy << 16);
}
__device__ __forceinline__ u16 pack1bf(float x) {
  u32 u = __float_as_uint(x);
  return (u16)((u + 0x7FFFu + ((u >> 16) & 1u)) >> 16);
}
__device__ __forceinline__ float bf1(u16 h)  { return __uint_as_float(((u32)h) << 16); }

__device__ __forceinline__ float redsum2(float v) {
  v += __shfl_xor(v, 16, 64);
  v += __shfl_xor(v, 32, 64);
  return v;
}
__device__ __forceinline__ float redmax2(float v) {
  v = fmaxf(v, __shfl_xor(v, 16, 64));
  v = fmaxf(v, __shfl_xor(v, 32, 64));
  return v;
}

// ---------- flat f32 -> bf16 pack ----------
__global__ __launch_bounds__(256) void pack_flat(const float* __restrict__ in,
                                                 u16* __restrict__ out) {
  size_t i = ((size_t)blockIdx.x * 256 + threadIdx.x) * 8;
  float4 a = *(const float4*)(in + i);
  float4 b = *(const float4*)(in + i + 4);
  uint4 o;
  o.x = packbf2(a.x, a.y); o.y = packbf2(a.z, a.w);
  o.z = packbf2(b.x, b.y); o.w = packbf2(b.z, b.w);
  *(uint4*)(out + i) = o;
}

// ---------- weight transpose-pack: f32 [K,N] -> bf16 [N,K], gridDim.z = layers ----------
__global__ __launch_bounds__(256) void pack_w_t(const float* __restrict__ in,
                                                u16* __restrict__ out, int K, int N) {
  __shared__ float tile[64][65];
  const int t  = threadIdx.x;
  const int n0 = blockIdx.x * 64, k0 = blockIdx.y * 64;
  in  += (size_t)blockIdx.z * K * N;
  out += (size_t)blockIdx.z * N * K;
  #pragma unroll
  for (int it = 0; it < 4; ++it) {
    int idx = it * 256 + t;
    int kk = idx >> 4, n4 = idx & 15;
    float4 v = *(const float4*)(in + (size_t)(k0 + kk) * N + n0 + n4 * 4);
    tile[kk][n4*4+0] = v.x; tile[kk][n4*4+1] = v.y;
    tile[kk][n4*4+2] = v.z; tile[kk][n4*4+3] = v.w;
  }
  __syncthreads();
  #pragma unroll
  for (int it = 0; it < 4; ++it) {
    int idx = it * 256 + t;
    int nn = idx >> 4, g = idx & 15;
    uint2 o;
    o.x = packbf2(tile[g*4+0][nn], tile[g*4+1][nn]);
    o.y = packbf2(tile[g*4+2][nn], tile[g*4+3][nn]);
    *(uint2*)(out + (size_t)(n0 + nn) * K + k0 + g * 4) = o;
  }
}

// ---------- bf16 MFMA GEMM (XCD-swizzled, optional dual via gridDim.z) ----------
// C[M,N] = A[M,K] @ B[K,N], Bt = B^T stored [N][K].
__global__ __launch_bounds__(256) void gemm_bf16(
    const u16* __restrict__ A, int lda,
    const u16* __restrict__ Bt, int ldb,
    const float* __restrict__ bias,
    float* __restrict__ outF, u16* __restrict__ outB, int ldc,
    int M, int N, int K, int relu, int accum,
    const u16* __restrict__ A2, const u16* __restrict__ Bt2,
    const float* __restrict__ bias2, u16* __restrict__ outB2)
{
  __shared__ u16 sA[128 * 32];  // [row][k], row stride 32
  __shared__ u16 sB[128 * 32];  // [col][k]

  // bijective XCD swizzle (m204): consecutive tiles land on one XCD's L2
  const int nwg  = gridDim.x * gridDim.y;
  const int orig = blockIdx.y * gridDim.x + blockIdx.x;
  const int q8   = nwg >> 3, r8 = nwg & 7;
  const int xcd  = orig & 7, idx8 = orig >> 3;
  const int wg   = (xcd < r8 ? xcd * (q8 + 1) : r8 * (q8 + 1) + (xcd - r8) * q8) + idx8;
  const int bx   = wg % gridDim.x, by = wg / gridDim.x;

  const u16* Ax = A; const u16* Bx = Bt;
  const float* biasx = bias;
  float* outFx = outF; u16* outBx = outB;
  if (blockIdx.z) { Ax = A2; Bx = Bt2; biasx = bias2; outFx = nullptr; outBx = outB2; }

  const int t    = threadIdx.x;
  const int lane = t & 63, wid = t >> 6;
  const int wr   = wid >> 1, wc = wid & 1;
  const int row0 = by * 128, col0 = bx * 128;
  const int kg   = lane >> 4, rl = lane & 15;

  f32x4 acc[4][4] = {};

  for (int k0 = 0; k0 < K; k0 += 32) {
    #pragma unroll
    for (int it = 0; it < 2; ++it) {
      int idx = it * 256 + t;
      int r = idx >> 2, seg = idx & 3;
      const u16* gA = Ax + (size_t)(row0 + r) * lda + k0 + seg * 8;
      const u16* gB = Bx + (size_t)(col0 + r) * ldb + k0 + seg * 8;
      __builtin_amdgcn_global_load_lds(
          (const __attribute__((address_space(1))) u32*)gA,
          (__attribute__((address_space(3))) u32*)(sA + (it * 256 + wid * 64) * 8),
          16, 0, 0);
      __builtin_amdgcn_global_load_lds(
          (const __attribute__((address_space(1))) u32*)gB,
          (__attribute__((address_space(3))) u32*)(sB + (it * 256 + wid * 64) * 8),
          16, 0, 0);
    }
    __syncthreads();
    bf16x8 af[4], bfr[4];
    #pragma unroll
    for (int m = 0; m < 4; ++m)
      af[m] = *(const bf16x8*)(sA + (wr * 64 + m * 16 + rl) * 32 + kg * 8);
    #pragma unroll
    for (int n = 0; n < 4; ++n)
      bfr[n] = *(const bf16x8*)(sB + (wc * 64 + n * 16 + rl) * 32 + kg * 8);
    #pragma unroll
    for (int m = 0; m < 4; ++m)
      #pragma unroll
      for (int n = 0; n < 4; ++n)
        acc[m][n] = __builtin_amdgcn_mfma_f32_16x16x32_bf16(af[m], bfr[n], acc[m][n], 0, 0, 0);
    __syncthreads();
  }

  #pragma unroll
  for (int m = 0; m < 4; ++m) {
    #pragma unroll
    for (int n = 0; n < 4; ++n) {
      const int col = col0 + wc * 64 + n * 16 + rl;
      const float bs = biasx ? biasx[col] : 0.f;
      #pragma unroll
      for (int q = 0; q < 4; ++q) {
        const int row = row0 + wr * 64 + m * 16 + kg * 4 + q;
        float v = acc[m][n][q] + bs;
        if (accum) v += outFx[(size_t)row * ldc + col];
        if (relu)  v = fmaxf(v, 0.f);
        if (outFx) outFx[(size_t)row * ldc + col] = v;
        if (outBx) outBx[(size_t)row * ldc + col] = pack1bf(v);
      }
    }
  }
}

// ---------- MFMA attention with distance-decay rescoring ----------
// Block = (b,h), 512 threads (8 waves). Each wave owns 4 row-tiles of 16 q-rows
// {w, 15-w, 16+w, 31-w} (balanced causal work). Swapped QK^T (mfma(K,Q) -> S^T)
// keeps softmax/cumsum math nearly lane-local. out may alias vbuf.
// launch_bounds(512,1): LDS caps at 1 block/CU anyway; allow up to 512 VGPRs
// so the 128-reg score array does NOT spill (r4: spills cost 220MB HBM traffic).
__global__ __launch_bounds__(512, 1) void attn_mfma(
    const u16* __restrict__ qk, const u16* __restrict__ vbuf,
    const float* __restrict__ gam, u16* __restrict__ out,
    int mask_excl, int zero_pad)
{
  __shared__ __align__(16) u8 kSb[65536];  // K/Q rows [512][64] bf16, byte ^= (row&7)<<4
  __shared__ __align__(16) u8 vTb[65536];  // V^T [64 d][512 k] bf16, byte ^= (d&7)<<4
  __shared__ __align__(16) u8 pChb[8192];  // per-wave 1KB P chunk buffers

  const int t    = threadIdx.x;
  const int lane = t & 63, wid = t >> 6;
  const int ql   = lane & 15, g = lane >> 4;
  const int bh   = blockIdx.x, b = bh >> 3, h = bh & 7;
  const size_t base = (size_t)b * SS * DDIM + (size_t)h * 64;

  float gv = gam[h];
  float sp = (gv > 0.f) ? (gv + log1pf(__expf(-gv))) : log1pf(__expf(gv));
  const float gamma = -sp;

  // ---- stage K/Q ----
  for (int it = 0; it < 8; ++it) {
    int idx = it * 512 + t;
    int j = idx >> 3, u = idx & 7;
    uint4 w = *(const uint4*)(qk + base + (size_t)j * DDIM + u * 8);
    *(uint4*)(kSb + ((j * 128 + u * 16) ^ ((j & 7) << 4))) = w;
  }
  // ---- stage V transposed; staggered d-order so (d&7) differs across lanes
  //      (fixes 16-way bank conflict on u16 scatter: 5.0M -> ~0) ----
  for (int it = 0; it < 8; ++it) {
    int idx = it * 512 + t;
    int j = idx >> 3, u = idx & 7;
    union { uint4 v4; u16 s[8]; } uu;
    uu.v4 = *(const uint4*)(vbuf + base + (size_t)j * DDIM + u * 8);
    #pragma unroll
    for (int dd0 = 0; dd0 < 8; ++dd0) {
      int dd = (dd0 + u) & 7;
      int d  = u * 8 + dd;
      *(u16*)(vTb + ((d * 1024 + 2 * j) ^ ((d & 7) << 4))) = uu.s[dd];
    }
  }
  __syncthreads();

  // diagonal-tile validity per (g, reg): k_local = 4g+reg vs q_local = ql
  bool vm[4];
  #pragma unroll
  for (int rg = 0; rg < 4; ++rg) {
    int kl = 4 * g + rg;
    vm[rg] = mask_excl ? (kl < ql) : (kl <= ql);
  }

  u8* pB = pChb + wid * 1024;
  const int swp = (ql & 3) << 4;

  #pragma unroll
  for (int ri = 0; ri < 4; ++ri) {
    int r0_ = (ri == 0) ? wid : (ri == 1) ? (15 - wid) : (ri == 2) ? (16 + wid) : (31 - wid);
    const int rs = __builtin_amdgcn_readfirstlane(r0_);
    const int i0 = rs * 16;

    // Q B-frags (row = i0+ql, d-slots g / 4+g)
    const int qrow = i0 + ql;
    const int qsw  = (qrow & 7) << 4;
    bf16x8 qf0 = *(const bf16x8*)(kSb + ((qrow * 128      + g * 16) ^ qsw));
    bf16x8 qf1 = *(const bf16x8*)(kSb + ((qrow * 128 + 64 + g * 16) ^ qsw));

    // ---- pass 1: scores S^T (raw dot), track m1 ----
    f32x4 sc[32];
    float m1 = -3.0e38f;
    #pragma unroll
    for (int kt = 0; kt < 32; ++kt) {
      if (kt <= rs) {
        const int krow = kt * 16 + ql;
        const int ksw  = (krow & 7) << 4;
        bf16x8 ka0 = *(const bf16x8*)(kSb + ((krow * 128      + g * 16) ^ ksw));
        bf16x8 ka1 = *(const bf16x8*)(kSb + ((krow * 128 + 64 + g * 16) ^ ksw));
        f32x4 d = {};
        d = __builtin_amdgcn_mfma_f32_16x16x32_bf16(ka0, qf0, d, 0, 0, 0);
        d = __builtin_amdgcn_mfma_f32_16x16x32_bf16(ka1, qf1, d, 0, 0, 0);
        sc[kt] = d;
        if (kt < rs) {
          #pragma unroll
          for (int rg = 0; rg < 4; ++rg) m1 = fmaxf(m1, d[rg]);
        } else {
          #pragma unroll
          for (int rg = 0; rg < 4; ++rg) m1 = fmaxf(m1, vm[rg] ? d[rg] : -3.0e38f);
        }
      }
    }
    m1 = redmax2(m1);
    const float m1s = 0.125f * m1;

    // ---- pass 2a: S1 ----
    float S1l = 0.f;
    #pragma unroll
    for (int kt = 0; kt < 32; ++kt) {
      if (kt <= rs) {
        const bool dg = (kt == rs);
        #pragma unroll
        for (int rg = 0; rg < 4; ++rg) {
          float e = __expf(0.125f * sc[kt][rg] - m1s);
          if (dg && !vm[rg]) e = 0.f;
          S1l += e;
        }
      }
    }
    const float S1   = redsum2(S1l);
    const float inv1 = 1.f / S1;

    // ---- pass 2b: cumsum + distance decay + rescoring ----
    float cbase = 0.f, m2 = -3.0e38f;
    const float qlf = (float)(i0 + ql);
    #pragma unroll
    for (int kt = 0; kt < 32; ++kt) {
      if (kt <= rs) {
        const bool dg = (kt == rs);
        float e0 = __expf(0.125f * sc[kt][0] - m1s);
        float e1 = __expf(0.125f * sc[kt][1] - m1s);
        float e2 = __expf(0.125f * sc[kt][2] - m1s);
        float e3 = __expf(0.125f * sc[kt][3] - m1s);
        if (dg) {
          if (!vm[0]) e0 = 0.f;
          if (!vm[1]) e1 = 0.f;
          if (!vm[2]) e2 = 0.f;
          if (!vm[3]) e3 = 0.f;
        }
        float p0 = e0, p1 = p0 + e1, p2s = p1 + e2, L = p2s + e3;
        float a16 = __shfl_up(L, 16, 64);
        float a32 = __shfl_up(L, 32, 64);
        float a48 = __shfl_up(L, 48, 64);
        float gp = (g >= 1 ? a16 : 0.f) + (g >= 2 ? a32 : 0.f) + (g >= 3 ? a48 : 0.f);
        float tt = __shfl(gp + L, ql + 48, 64);
        const float pbase = cbase + gp;
        const float pf = qlf - (float)(kt * 16 + 4 * g);
        float ipr[4] = {p0, p1, p2s, L};
        #pragma unroll
        for (int rg = 0; rg < 4; ++rg) {
          float rem  = fmaxf((S1 - (pbase + ipr[rg])) * inv1, 0.f);
          float pos  = pf - (float)rg;
          float dist = sqrtf(fmaxf(rem * pos, 0.f));
          float eff  = fmaxf(__expf(gamma * dist), 1e-5f);  // eff <= 1 since gamma < 0
          float s2 = 0.125f * sc[kt][rg] * eff;
          if (dg && !vm[rg]) s2 = -3.0e38f;
          sc[kt][rg] = s2;
          m2 = fmaxf(m2, s2);
        }
        cbase += tt;
      }
    }
    m2 = redmax2(m2);

    // ---- pass 3: e2, S2 ----
    float S2l = 0.f;
    #pragma unroll
    for (int kt = 0; kt < 32; ++kt) {
      if (kt <= rs) {
        #pragma unroll
        for (int rg = 0; rg < 4; ++rg) {
          float e = __expf(sc[kt][rg] - m2);
          sc[kt][rg] = e;
          S2l += e;
        }
      }
    }
    const float S2   = redsum2(S2l);
    const float inv2 = 1.f / fmaxf(S2, 1e-30f);

    // ---- pass 4: PV via MFMA, P through per-wave LDS chunk buffer ----
    f32x4 oacc[4] = {};
    #pragma unroll
    for (int c = 0; c < 16; ++c) {
      if (2 * c <= rs) {
        const bool t2v = (2 * c + 1 <= rs);
        u32 w0 = packbf2(sc[2*c][0] * inv2, sc[2*c][1] * inv2);
        u32 w1 = packbf2(sc[2*c][2] * inv2, sc[2*c][3] * inv2);
        u32 w2 = t2v ? packbf2(sc[2*c+1][0] * inv2, sc[2*c+1][1] * inv2) : 0u;
        u32 w3 = t2v ? packbf2(sc[2*c+1][2] * inv2, sc[2*c+1][3] * inv2) : 0u;
        *(u32*)(pB + ((ql * 64 +      8 * g    ) ^ swp)) = w0;
        *(u32*)(pB + ((ql * 64 +      8 * g + 4) ^ swp)) = w1;
        *(u32*)(pB + ((ql * 64 + 32 + 8 * g    ) ^ swp)) = w2;
        *(u32*)(pB + ((ql * 64 + 32 + 8 * g + 4) ^ swp)) = w3;
        bf16x8 pa = *(const bf16x8*)(pB + ((ql * 64 + 16 * g) ^ swp));
        #pragma unroll
        for (int n = 0; n < 4; ++n) {
          const int d = n * 16 + ql;
          bf16x8 vb = *(const bf16x8*)(vTb + ((d * 1024 + 64 * c + 16 * g) ^ ((d & 7) << 4)));
          oacc[n] = __builtin_amdgcn_mfma_f32_16x16x32_bf16(pa, vb, oacc[n], 0, 0, 0);
        }
      }
    }

    // ---- store O tile: q_out = i0 + 4g + reg, d = n*16 + ql ----
    #pragma unroll
    for (int n = 0; n < 4; ++n) {
      #pragma unroll
      for (int rg = 0; rg < 4; ++rg) {
        const int qo = i0 + 4 * g + rg;
        float val = oacc[n][rg];
        if (zero_pad && qo == 0) val = 0.f;
        out[base + (size_t)qo * DDIM + n * 16 + ql] = pack1bf(val);
      }
    }
  }
}

// ---------- fused residual + LayerNorm (dual f32/bf16 out) ----------
__global__ __launch_bounds__(256) void ln_kernel(
    const float* __restrict__ a, const float* __restrict__ bsrc,
    const float* __restrict__ g, const float* __restrict__ be,
    float* __restrict__ outF, u16* __restrict__ outB)
{
  const int lane = threadIdx.x & 63, w = threadIdx.x >> 6;
  const size_t row = (size_t)blockIdx.x * 4 + w;
  const float* pa = a    + row * DDIM;
  const float* pb = bsrc + row * DDIM;
  float v[8];
  float sum = 0.f;
  #pragma unroll
  for (int c = 0; c < 2; ++c) {
    float4 va = *(const float4*)(pa + c * 256 + lane * 4);
    float4 vb = *(const float4*)(pb + c * 256 + lane * 4);
    v[c*4+0] = va.x + vb.x; v[c*4+1] = va.y + vb.y;
    v[c*4+2] = va.z + vb.z; v[c*4+3] = va.w + vb.w;
    sum += v[c*4+0] + v[c*4+1] + v[c*4+2] + v[c*4+3];
  }
  #pragma unroll
  for (int off = 32; off > 0; off >>= 1) sum += __shfl_xor(sum, off, 64);
  const float mean = sum * (1.f / 512.f);
  float var = 0.f;
  #pragma unroll
  for (int k = 0; k < 8; ++k) { float dd = v[k] - mean; var = fmaf(dd, dd, var); }
  #pragma unroll
  for (int off = 32; off > 0; off >>= 1) var += __shfl_xor(var, off, 64);
  var *= (1.f / 512.f);
  const float inv = rsqrtf(var + 1e-5f);
  #pragma unroll
  for (int c = 0; c < 2; ++c) {
    float4 gg = *(const float4*)(g  + c * 256 + lane * 4);
    float4 bb = *(const float4*)(be + c * 256 + lane * 4);
    float4 o;
    o.x = (v[c*4+0] - mean) * inv * gg.x + bb.x;
    o.y = (v[c*4+1] - mean) * inv * gg.y + bb.y;
    o.z = (v[c*4+2] - mean) * inv * gg.z + bb.z;
    o.w = (v[c*4+3] - mean) * inv * gg.w + bb.w;
    const size_t off4 = row * DDIM + c * 256 + lane * 4;
    if (outF) *(float4*)(outF + off4) = o;
    if (outB) {
      uint2 p;
      p.x = packbf2(o.x, o.y); p.y = packbf2(o.z, o.w);
      *(uint2*)(outB + off4) = p;
    }
  }
}

// ---------- orchestration ----------
extern "C" void kernel_launch(void* const* d_in, const int* in_sizes, int n_in,
                              void* d_out, int out_size, void* d_ws, size_t ws_size,
                              hipStream_t stream) {
  const float* qe  = (const float*)d_in[0];
  const float* qa  = (const float*)d_in[1];
  const float* Wk  = (const float*)d_in[2];
  const float* bk  = (const float*)d_in[3];
  const float* Wv  = (const float*)d_in[4];
  const float* bv  = (const float*)d_in[5];
  const float* Wo  = (const float*)d_in[6];
  const float* bo  = (const float*)d_in[7];
  const float* gm  = (const float*)d_in[8];
  const float* l1g = (const float*)d_in[9];
  const float* l1b = (const float*)d_in[10];
  const float* W1  = (const float*)d_in[11];
  const float* b1  = (const float*)d_in[12];
  const float* W2  = (const float*)d_in[13];
  const float* b2  = (const float*)d_in[14];
  const float* l2g = (const float*)d_in[15];
  const float* l2b = (const float*)d_in[16];

  char* ws = (char*)d_ws;
  u16* WT = (u16*)ws;                              // 17.3 MB packed weights
  u16* A0 = (u16*)(ws + ((size_t)18  << 20));      // 16 MiB bf16 act slots
  u16* A1 = (u16*)(ws + ((size_t)34  << 20));
  u16* A2 = (u16*)(ws + ((size_t)50  << 20));
  u16* A3 = (u16*)(ws + ((size_t)66  << 20));
  float* F0 = (float*)(ws + ((size_t)82  << 20));  // 32 MiB f32 slots
  float* F1 = (float*)(ws + ((size_t)114 << 20));
  u16* Amid = (u16*)(ws + ((size_t)146 << 20));    // 64 MiB FFN mid (if ws allows)
  const bool bigws = ws_size >= ((size_t)211 << 20);

  u16* WkT = WT;                    // [L][512][512]
  u16* WvT = WT + (size_t)3 * 262144;
  u16* WoT = WT + (size_t)6 * 262144;
  u16* W1T = WT + (size_t)9 * 262144;              // [L][2048][512]
  u16* W2T = W1T + (size_t)3 * 1048576;            // [L][512][2048]

  pack_w_t<<<dim3(8, 8, 3),  256, 0, stream>>>(Wk, WkT, 512, 512);
  pack_w_t<<<dim3(8, 8, 3),  256, 0, stream>>>(Wv, WvT, 512, 512);
  pack_w_t<<<dim3(8, 8, 3),  256, 0, stream>>>(Wo, WoT, 512, 512);
  pack_w_t<<<dim3(32, 8, 3), 256, 0, stream>>>(W1, W1T, 512, 2048);
  pack_w_t<<<dim3(8, 32, 3), 256, 0, stream>>>(W2, W2T, 2048, 512);
  pack_flat<<<4096, 256, 0, stream>>>(qa, A0);
  pack_flat<<<4096, 256, 0, stream>>>(qe, A1);

  auto gemm = [&](const u16* A, int lda, const u16* Bt, int ldb, const float* bias,
                  float* outF, u16* outB, int ldc, int M, int N, int K,
                  int relu, int accum) {
    gemm_bf16<<<dim3(N / 128, M / 128, 1), 256, 0, stream>>>(
        A, lda, Bt, ldb, bias, outF, outB, ldc, M, N, K, relu, accum,
        nullptr, nullptr, nullptr, nullptr);
  };
  // fused qk + v projection (z=0: qk, z=1: v)
  auto gemm2 = [&](const u16* Aq, const u16* BtQ, const float* biasQ, u16* outQ,
                   const u16* Av, const u16* BtV, const float* biasV, u16* outV) {
    gemm_bf16<<<dim3(4, 128, 2), 256, 0, stream>>>(
        Aq, 512, BtQ, 512, biasQ, nullptr, outQ, 512, MR, 512, 512, 0, 0,
        Av, BtV, biasV, outV);
  };

  auto layer = [&](int li, const u16* qbf, const float* qf32, const u16* vbf,
                   int excl, int zp, int pos,
                   float* lnF, u16* lnB, u16* midB, float* y2F, u16* y2B) {
    const float* bk_l = bk + (size_t)li * DDIM;
    const float* bv_l = bv + (size_t)li * DDIM;
    const float* bo_l = bo + (size_t)li * DDIM;
    const float* gm_l = gm + (size_t)li * HH;
    const float* g1   = l1g + (size_t)li * DDIM;
    const float* be1  = l1b + (size_t)li * DDIM;
    const float* g2   = l2g + (size_t)li * DDIM;
    const float* be2  = l2b + (size_t)li * DDIM;
    const float* b1_l = b1 + (size_t)li * DFFN;
    const float* b2_l = b2 + (size_t)li * DDIM;
    const u16* WkT_l = WkT + (size_t)li * 262144;
    const u16* WvT_l = WvT + (size_t)li * 262144;
    const u16* WoT_l = WoT + (size_t)li * 262144;
    const u16* W1T_l = W1T + (size_t)li * 1048576;
    const u16* W2T_l = W2T + (size_t)li * 1048576;

    gemm2(qbf, WkT_l, bk_l, A2, vbf, WvT_l, bv_l, A3);
    attn_mfma<<<BB * HH, 512, 0, stream>>>(A2, A3, gm_l, A3, excl, zp);
    gemm(A3, 512, WoT_l, 512, bo_l, F0, nullptr, 512, MR, 512, 512, 0, 0);
    ln_kernel<<<MR / 4, 256, 0, stream>>>(qf32, F0, g1, be1, lnF, lnB);
    if (pos) {
      if (bigws) {
        gemm(lnB, 512, W1T_l, 512, b1_l, nullptr, Amid, DFFN, MR, DFFN, 512, 1, 0);
        gemm(Amid, DFFN, W2T_l, DFFN, b2_l, F0, nullptr, 512, MR, 512, DFFN, 0, 0);
      } else {
        for (int c = 0; c < 4; ++c) {
          gemm(lnB, 512, W1T_l + (size_t)c * 512 * 512, 512, b1_l + c * 512,
               nullptr, midB, 512, MR, 512, 512, 1, 0);
          gemm(midB, 512, W2T_l + (size_t)c * 512, 2048, (c == 0) ? b2_l : nullptr,
               F0, nullptr, 512, MR, 512, 512, 0, (c > 0) ? 1 : 0);
        }
      }
      ln_kernel<<<MR / 4, 256, 0, stream>>>(lnF, F0, g2, be2, y2F, y2B);
    }
  };

  layer(0, A0, qa, A0, 0, 0, 1, F1, A2, A3, nullptr, A0);
  layer(1, A1, qe, A1, 0, 0, 0, F1, A1, nullptr, nullptr, nullptr);
  layer(2, A1, F1, A0, 1, 1, 1, F1, A1, A2, (float*)d_out, nullptr);
}

// Round 6
// 1081.094 us; speedup vs baseline: 8.7205x; 1.0525x over previous
//
#include <hip/hip_runtime.h>

#define BB   32
#define SS   512
#define DDIM 512
#define HH   8
#define DFFN 2048
#define MR   (BB*SS)   // 16384 rows

typedef unsigned int   u32;
typedef unsigned short u16;
typedef unsigned char  u8;
typedef __attribute__((ext_vector_type(8))) short bf16x8;
typedef __attribute__((ext_vector_type(4))) float f32x4;
typedef __attribute__((ext_vector_type(2))) _Float16 h16x2;

// ---------- bf16 helpers ----------
__device__ __forceinline__ u32 packbf2(float x, float y) {
  u32 ux = __float_as_uint(x), uy = __float_as_uint(y);
  u32 hx = (ux + 0x7FFFu + ((ux >> 16) & 1u)) >> 16;
  u32 hy = (uy + 0x7FFFu + ((uy >> 16) & 1u)) >> 16;
  return hx | (hy << 16);
}
__device__ __forceinline__ u16 pack1bf(float x) {
  u32 u = __float_as_uint(x);
  return (u16)((u + 0x7FFFu + ((u >> 16) & 1u)) >> 16);
}
__device__ __forceinline__ float bf1(u16 h)  { return __uint_as_float(((u32)h) << 16); }

__device__ __forceinline__ float redsum2(float v) {
  v += __shfl_xor(v, 16, 64);
  v += __shfl_xor(v, 32, 64);
  return v;
}
__device__ __forceinline__ float redmax2(float v) {
  v = fmaxf(v, __shfl_xor(v, 16, 64));
  v = fmaxf(v, __shfl_xor(v, 32, 64));
  return v;
}

// ---------- flat f32 -> bf16 pack ----------
__global__ __launch_bounds__(256) void pack_flat(const float* __restrict__ in,
                                                 u16* __restrict__ out) {
  size_t i = ((size_t)blockIdx.x * 256 + threadIdx.x) * 8;
  float4 a = *(const float4*)(in + i);
  float4 b = *(const float4*)(in + i + 4);
  uint4 o;
  o.x = packbf2(a.x, a.y); o.y = packbf2(a.z, a.w);
  o.z = packbf2(b.x, b.y); o.w = packbf2(b.z, b.w);
  *(uint4*)(out + i) = o;
}

// ---------- weight transpose-pack: f32 [K,N] -> bf16 [N,K], gridDim.z = layers ----------
__global__ __launch_bounds__(256) void pack_w_t(const float* __restrict__ in,
                                                u16* __restrict__ out, int K, int N) {
  __shared__ float tile[64][65];
  const int t  = threadIdx.x;
  const int n0 = blockIdx.x * 64, k0 = blockIdx.y * 64;
  in  += (size_t)blockIdx.z * K * N;
  out += (size_t)blockIdx.z * N * K;
  #pragma unroll
  for (int it = 0; it < 4; ++it) {
    int idx = it * 256 + t;
    int kk = idx >> 4, n4 = idx & 15;
    float4 v = *(const float4*)(in + (size_t)(k0 + kk) * N + n0 + n4 * 4);
    tile[kk][n4*4+0] = v.x; tile[kk][n4*4+1] = v.y;
    tile[kk][n4*4+2] = v.z; tile[kk][n4*4+3] = v.w;
  }
  __syncthreads();
  #pragma unroll
  for (int it = 0; it < 4; ++it) {
    int idx = it * 256 + t;
    int nn = idx >> 4, g = idx & 15;
    uint2 o;
    o.x = packbf2(tile[g*4+0][nn], tile[g*4+1][nn]);
    o.y = packbf2(tile[g*4+2][nn], tile[g*4+3][nn]);
    *(uint2*)(out + (size_t)(n0 + nn) * K + k0 + g * 4) = o;
  }
}

// ---------- bf16 MFMA GEMM (XCD-swizzled, optional dual via gridDim.z) ----------
// C[M,N] = A[M,K] @ B[K,N], Bt = B^T stored [N][K].
__global__ __launch_bounds__(256) void gemm_bf16(
    const u16* __restrict__ A, int lda,
    const u16* __restrict__ Bt, int ldb,
    const float* __restrict__ bias,
    float* __restrict__ outF, u16* __restrict__ outB, int ldc,
    int M, int N, int K, int relu, int accum,
    const u16* __restrict__ A2, const u16* __restrict__ Bt2,
    const float* __restrict__ bias2, u16* __restrict__ outB2)
{
  __shared__ u16 sA[128 * 32];  // [row][k], row stride 32
  __shared__ u16 sB[128 * 32];  // [col][k]

  // bijective XCD swizzle (m204): consecutive tiles land on one XCD's L2
  const int nwg  = gridDim.x * gridDim.y;
  const int orig = blockIdx.y * gridDim.x + blockIdx.x;
  const int q8   = nwg >> 3, r8 = nwg & 7;
  const int xcd  = orig & 7, idx8 = orig >> 3;
  const int wg   = (xcd < r8 ? xcd * (q8 + 1) : r8 * (q8 + 1) + (xcd - r8) * q8) + idx8;
  const int bx   = wg % gridDim.x, by = wg / gridDim.x;

  const u16* Ax = A; const u16* Bx = Bt;
  const float* biasx = bias;
  float* outFx = outF; u16* outBx = outB;
  if (blockIdx.z) { Ax = A2; Bx = Bt2; biasx = bias2; outFx = nullptr; outBx = outB2; }

  const int t    = threadIdx.x;
  const int lane = t & 63, wid = t >> 6;
  const int wr   = wid >> 1, wc = wid & 1;
  const int row0 = by * 128, col0 = bx * 128;
  const int kg   = lane >> 4, rl = lane & 15;

  f32x4 acc[4][4] = {};

  for (int k0 = 0; k0 < K; k0 += 32) {
    #pragma unroll
    for (int it = 0; it < 2; ++it) {
      int idx = it * 256 + t;
      int r = idx >> 2, seg = idx & 3;
      const u16* gA = Ax + (size_t)(row0 + r) * lda + k0 + seg * 8;
      const u16* gB = Bx + (size_t)(col0 + r) * ldb + k0 + seg * 8;
      __builtin_amdgcn_global_load_lds(
          (const __attribute__((address_space(1))) u32*)gA,
          (__attribute__((address_space(3))) u32*)(sA + (it * 256 + wid * 64) * 8),
          16, 0, 0);
      __builtin_amdgcn_global_load_lds(
          (const __attribute__((address_space(1))) u32*)gB,
          (__attribute__((address_space(3))) u32*)(sB + (it * 256 + wid * 64) * 8),
          16, 0, 0);
    }
    __syncthreads();
    bf16x8 af[4], bfr[4];
    #pragma unroll
    for (int m = 0; m < 4; ++m)
      af[m] = *(const bf16x8*)(sA + (wr * 64 + m * 16 + rl) * 32 + kg * 8);
    #pragma unroll
    for (int n = 0; n < 4; ++n)
      bfr[n] = *(const bf16x8*)(sB + (wc * 64 + n * 16 + rl) * 32 + kg * 8);
    #pragma unroll
    for (int m = 0; m < 4; ++m)
      #pragma unroll
      for (int n = 0; n < 4; ++n)
        acc[m][n] = __builtin_amdgcn_mfma_f32_16x16x32_bf16(af[m], bfr[n], acc[m][n], 0, 0, 0);
    __syncthreads();
  }

  #pragma unroll
  for (int m = 0; m < 4; ++m) {
    #pragma unroll
    for (int n = 0; n < 4; ++n) {
      const int col = col0 + wc * 64 + n * 16 + rl;
      const float bs = biasx ? biasx[col] : 0.f;
      #pragma unroll
      for (int q = 0; q < 4; ++q) {
        const int row = row0 + wr * 64 + m * 16 + kg * 4 + q;
        float v = acc[m][n][q] + bs;
        if (accum) v += outFx[(size_t)row * ldc + col];
        if (relu)  v = fmaxf(v, 0.f);
        if (outFx) outFx[(size_t)row * ldc + col] = v;
        if (outBx) outBx[(size_t)row * ldc + col] = pack1bf(v);
      }
    }
  }
}

// ---------- MFMA attention with distance-decay rescoring ----------
// Block = (b,h), 512 threads (8 waves). Each wave owns 4 row-tiles of 16 q-rows
// {w, 15-w, 16+w, 31-w}. Swapped QK^T (mfma(K,Q) -> S^T) keeps the math
// per-q-row lane-local. Score state held as PACKED f16 pairs (64 VGPRs, not
// 128) so the whole pipeline fits in registers — r5 showed f32x4 sc[32]
// spilled (~220MB scratch traffic/dispatch = the entire 200us runtime).
// waves_per_eu(1,2): LDS (136KB) caps at 1 block/CU = 2 waves/EU, so let the
// allocator use up to 256 VGPRs instead of its 128 default.
__global__ __attribute__((amdgpu_flat_work_group_size(512, 512)))
           __attribute__((amdgpu_waves_per_eu(1, 2)))
void attn_mfma(
    const u16* __restrict__ qk, const u16* __restrict__ vbuf,
    const float* __restrict__ gam, u16* __restrict__ out,
    int mask_excl, int zero_pad)
{
  __shared__ __align__(16) u8 kSb[65536];  // K/Q rows [512][64] bf16, byte ^= (row&7)<<4
  __shared__ __align__(16) u8 vTb[65536];  // V^T [64 d][512 k] bf16, byte ^= (d&7)<<4
  __shared__ __align__(16) u8 pChb[8192];  // per-wave 1KB P chunk buffers

  const int t    = threadIdx.x;
  const int lane = t & 63, wid = t >> 6;
  const int ql   = lane & 15, g = lane >> 4;
  const int bh   = blockIdx.x, b = bh >> 3, h = bh & 7;
  const size_t base = (size_t)b * SS * DDIM + (size_t)h * 64;

  float gv = gam[h];
  float sp = (gv > 0.f) ? (gv + log1pf(__expf(-gv))) : log1pf(__expf(gv));
  const float gamma = -sp;

  // ---- stage K/Q ----
  for (int it = 0; it < 8; ++it) {
    int idx = it * 512 + t;
    int j = idx >> 3, u = idx & 7;
    uint4 w = *(const uint4*)(qk + base + (size_t)j * DDIM + u * 8);
    *(uint4*)(kSb + ((j * 128 + u * 16) ^ ((j & 7) << 4))) = w;
  }
  // ---- stage V transposed; staggered d-order so (d&7) differs across lanes ----
  for (int it = 0; it < 8; ++it) {
    int idx = it * 512 + t;
    int j = idx >> 3, u = idx & 7;
    union { uint4 v4; u16 s[8]; } uu;
    uu.v4 = *(const uint4*)(vbuf + base + (size_t)j * DDIM + u * 8);
    #pragma unroll
    for (int dd0 = 0; dd0 < 8; ++dd0) {
      int dd = (dd0 + u) & 7;
      int d  = u * 8 + dd;
      *(u16*)(vTb + ((d * 1024 + 2 * j) ^ ((d & 7) << 4))) = uu.s[dd];
    }
  }
  __syncthreads();

  // diagonal-tile validity per (g, reg): k_local = 4g+reg vs q_local = ql
  bool vm[4];
  #pragma unroll
  for (int rg = 0; rg < 4; ++rg) {
    int kl = 4 * g + rg;
    vm[rg] = mask_excl ? (kl < ql) : (kl <= ql);
  }

  u8* pB = pChb + wid * 1024;
  const int swp = (ql & 3) << 4;

  #pragma unroll
  for (int ri = 0; ri < 4; ++ri) {
    int r0_ = (ri == 0) ? wid : (ri == 1) ? (15 - wid) : (ri == 2) ? (16 + wid) : (31 - wid);
    const int rs = __builtin_amdgcn_readfirstlane(r0_);
    const int i0 = rs * 16;

    // Q B-frags (row = i0+ql, d-slots g / 4+g)
    const int qrow = i0 + ql;
    const int qsw  = (qrow & 7) << 4;
    bf16x8 qf0 = *(const bf16x8*)(kSb + ((qrow * 128      + g * 16) ^ qsw));
    bf16x8 qf1 = *(const bf16x8*)(kSb + ((qrow * 128 + 64 + g * 16) ^ qsw));

    // ---- pass 1: scores S^T (scaled 1/8), stored as f16 pairs; track m1 ----
    h16x2 sch[32][2];
    float m1 = -3.0e38f;
    #pragma unroll
    for (int kt = 0; kt < 32; ++kt) {
      if (kt <= rs) {
        const int krow = kt * 16 + ql;
        const int ksw  = (krow & 7) << 4;
        bf16x8 ka0 = *(const bf16x8*)(kSb + ((krow * 128      + g * 16) ^ ksw));
        bf16x8 ka1 = *(const bf16x8*)(kSb + ((krow * 128 + 64 + g * 16) ^ ksw));
        f32x4 d = {};
        d = __builtin_amdgcn_mfma_f32_16x16x32_bf16(ka0, qf0, d, 0, 0, 0);
        d = __builtin_amdgcn_mfma_f32_16x16x32_bf16(ka1, qf1, d, 0, 0, 0);
        float d0 = d[0] * 0.125f, d1 = d[1] * 0.125f;
        float d2 = d[2] * 0.125f, d3 = d[3] * 0.125f;
        sch[kt][0] = h16x2{(_Float16)d0, (_Float16)d1};
        sch[kt][1] = h16x2{(_Float16)d2, (_Float16)d3};
        if (kt < rs) {
          m1 = fmaxf(m1, fmaxf(fmaxf(d0, d1), fmaxf(d2, d3)));
        } else {
          m1 = fmaxf(m1, vm[0] ? d0 : -3.0e38f);
          m1 = fmaxf(m1, vm[1] ? d1 : -3.0e38f);
          m1 = fmaxf(m1, vm[2] ? d2 : -3.0e38f);
          m1 = fmaxf(m1, vm[3] ? d3 : -3.0e38f);
        }
      }
    }
    m1 = redmax2(m1);

    // ---- pass 2a: S1 ----
    float S1l = 0.f;
    #pragma unroll
    for (int kt = 0; kt < 32; ++kt) {
      if (kt <= rs) {
        const bool dg = (kt == rs);
        float s0 = (float)sch[kt][0].x, s1v = (float)sch[kt][0].y;
        float s2v = (float)sch[kt][1].x, s3v = (float)sch[kt][1].y;
        float e0 = __expf(s0 - m1), e1 = __expf(s1v - m1);
        float e2 = __expf(s2v - m1), e3 = __expf(s3v - m1);
        if (dg) {
          if (!vm[0]) e0 = 0.f;
          if (!vm[1]) e1 = 0.f;
          if (!vm[2]) e2 = 0.f;
          if (!vm[3]) e3 = 0.f;
        }
        S1l += (e0 + e1) + (e2 + e3);
      }
    }
    const float S1   = redsum2(S1l);
    const float inv1 = 1.f / S1;

    // ---- pass 2b: cumsum + distance decay + rescoring (store s2 as f16) ----
    float cbase = 0.f, m2 = -3.0e38f;
    const float qlf = (float)(i0 + ql);
    #pragma unroll
    for (int kt = 0; kt < 32; ++kt) {
      if (kt <= rs) {
        const bool dg = (kt == rs);
        float sv[4];
        sv[0] = (float)sch[kt][0].x; sv[1] = (float)sch[kt][0].y;
        sv[2] = (float)sch[kt][1].x; sv[3] = (float)sch[kt][1].y;
        float e0 = __expf(sv[0] - m1);
        float e1 = __expf(sv[1] - m1);
        float e2 = __expf(sv[2] - m1);
        float e3 = __expf(sv[3] - m1);
        if (dg) {
          if (!vm[0]) e0 = 0.f;
          if (!vm[1]) e1 = 0.f;
          if (!vm[2]) e2 = 0.f;
          if (!vm[3]) e3 = 0.f;
        }
        float p0 = e0, p1 = p0 + e1, p2s = p1 + e2, L = p2s + e3;
        float a16 = __shfl_up(L, 16, 64);
        float a32 = __shfl_up(L, 32, 64);
        float a48 = __shfl_up(L, 48, 64);
        float gp = (g >= 1 ? a16 : 0.f) + (g >= 2 ? a32 : 0.f) + (g >= 3 ? a48 : 0.f);
        float tt = __shfl(gp + L, ql + 48, 64);
        const float pbase = cbase + gp;
        const float pf = qlf - (float)(kt * 16 + 4 * g);
        float ipr[4] = {p0, p1, p2s, L};
        float s2o[4];
        #pragma unroll
        for (int rg = 0; rg < 4; ++rg) {
          float rem  = fmaxf((S1 - (pbase + ipr[rg])) * inv1, 0.f);
          float pos  = pf - (float)rg;
          float dist = sqrtf(fmaxf(rem * pos, 0.f));
          float eff  = fmaxf(__expf(gamma * dist), 1e-5f);  // eff <= 1 since gamma < 0
          float s2 = sv[rg] * eff;
          if (dg && !vm[rg]) s2 = -60000.f;   // f16-finite "-inf"
          s2o[rg] = s2;
          m2 = fmaxf(m2, s2);
        }
        sch[kt][0] = h16x2{(_Float16)s2o[0], (_Float16)s2o[1]};
        sch[kt][1] = h16x2{(_Float16)s2o[2], (_Float16)s2o[3]};
        cbase += tt;
      }
    }
    m2 = redmax2(m2);

    // ---- pass 3: e2 (stored back as f16), S2 ----
    float S2l = 0.f;
    #pragma unroll
    for (int kt = 0; kt < 32; ++kt) {
      if (kt <= rs) {
        float e0 = __expf((float)sch[kt][0].x - m2);
        float e1 = __expf((float)sch[kt][0].y - m2);
        float e2 = __expf((float)sch[kt][1].x - m2);
        float e3 = __expf((float)sch[kt][1].y - m2);
        sch[kt][0] = h16x2{(_Float16)e0, (_Float16)e1};
        sch[kt][1] = h16x2{(_Float16)e2, (_Float16)e3};
        S2l += (e0 + e1) + (e2 + e3);
      }
    }
    const float S2   = redsum2(S2l);
    const float inv2 = 1.f / fmaxf(S2, 1e-30f);

    // ---- pass 4: PV via MFMA, P through per-wave LDS chunk buffer ----
    f32x4 oacc[4] = {};
    #pragma unroll
    for (int c = 0; c < 16; ++c) {
      if (2 * c <= rs) {
        const bool t2v = (2 * c + 1 <= rs);
        u32 w0 = packbf2((float)sch[2*c][0].x * inv2, (float)sch[2*c][0].y * inv2);
        u32 w1 = packbf2((float)sch[2*c][1].x * inv2, (float)sch[2*c][1].y * inv2);
        u32 w2 = t2v ? packbf2((float)sch[2*c+1][0].x * inv2, (float)sch[2*c+1][0].y * inv2) : 0u;
        u32 w3 = t2v ? packbf2((float)sch[2*c+1][1].x * inv2, (float)sch[2*c+1][1].y * inv2) : 0u;
        *(u32*)(pB + ((ql * 64 +      8 * g    ) ^ swp)) = w0;
        *(u32*)(pB + ((ql * 64 +      8 * g + 4) ^ swp)) = w1;
        *(u32*)(pB + ((ql * 64 + 32 + 8 * g    ) ^ swp)) = w2;
        *(u32*)(pB + ((ql * 64 + 32 + 8 * g + 4) ^ swp)) = w3;
        bf16x8 pa = *(const bf16x8*)(pB + ((ql * 64 + 16 * g) ^ swp));
        #pragma unroll
        for (int n = 0; n < 4; ++n) {
          const int d = n * 16 + ql;
          bf16x8 vb = *(const bf16x8*)(vTb + ((d * 1024 + 64 * c + 16 * g) ^ ((d & 7) << 4)));
          oacc[n] = __builtin_amdgcn_mfma_f32_16x16x32_bf16(pa, vb, oacc[n], 0, 0, 0);
        }
      }
    }

    // ---- store O tile: q_out = i0 + 4g + reg, d = n*16 + ql ----
    #pragma unroll
    for (int n = 0; n < 4; ++n) {
      #pragma unroll
      for (int rg = 0; rg < 4; ++rg) {
        const int qo = i0 + 4 * g + rg;
        float val = oacc[n][rg];
        if (zero_pad && qo == 0) val = 0.f;
        out[base + (size_t)qo * DDIM + n * 16 + ql] = pack1bf(val);
      }
    }
  }
}

// ---------- fused residual + LayerNorm (dual f32/bf16 out) ----------
__global__ __launch_bounds__(256) void ln_kernel(
    const float* __restrict__ a, const float* __restrict__ bsrc,
    const float* __restrict__ g, const float* __restrict__ be,
    float* __restrict__ outF, u16* __restrict__ outB)
{
  const int lane = threadIdx.x & 63, w = threadIdx.x >> 6;
  const size_t row = (size_t)blockIdx.x * 4 + w;
  const float* pa = a    + row * DDIM;
  const float* pb = bsrc + row * DDIM;
  float v[8];
  float sum = 0.f;
  #pragma unroll
  for (int c = 0; c < 2; ++c) {
    float4 va = *(const float4*)(pa + c * 256 + lane * 4);
    float4 vb = *(const float4*)(pb + c * 256 + lane * 4);
    v[c*4+0] = va.x + vb.x; v[c*4+1] = va.y + vb.y;
    v[c*4+2] = va.z + vb.z; v[c*4+3] = va.w + vb.w;
    sum += v[c*4+0] + v[c*4+1] + v[c*4+2] + v[c*4+3];
  }
  #pragma unroll
  for (int off = 32; off > 0; off >>= 1) sum += __shfl_xor(sum, off, 64);
  const float mean = sum * (1.f / 512.f);
  float var = 0.f;
  #pragma unroll
  for (int k = 0; k < 8; ++k) { float dd = v[k] - mean; var = fmaf(dd, dd, var); }
  #pragma unroll
  for (int off = 32; off > 0; off >>= 1) var += __shfl_xor(var, off, 64);
  var *= (1.f / 512.f);
  const float inv = rsqrtf(var + 1e-5f);
  #pragma unroll
  for (int c = 0; c < 2; ++c) {
    float4 gg = *(const float4*)(g  + c * 256 + lane * 4);
    float4 bb = *(const float4*)(be + c * 256 + lane * 4);
    float4 o;
    o.x = (v[c*4+0] - mean) * inv * gg.x + bb.x;
    o.y = (v[c*4+1] - mean) * inv * gg.y + bb.y;
    o.z = (v[c*4+2] - mean) * inv * gg.z + bb.z;
    o.w = (v[c*4+3] - mean) * inv * gg.w + bb.w;
    const size_t off4 = row * DDIM + c * 256 + lane * 4;
    if (outF) *(float4*)(outF + off4) = o;
    if (outB) {
      uint2 p;
      p.x = packbf2(o.x, o.y); p.y = packbf2(o.z, o.w);
      *(uint2*)(outB + off4) = p;
    }
  }
}

// ---------- orchestration ----------
extern "C" void kernel_launch(void* const* d_in, const int* in_sizes, int n_in,
                              void* d_out, int out_size, void* d_ws, size_t ws_size,
                              hipStream_t stream) {
  const float* qe  = (const float*)d_in[0];
  const float* qa  = (const float*)d_in[1];
  const float* Wk  = (const float*)d_in[2];
  const float* bk  = (const float*)d_in[3];
  const float* Wv  = (const float*)d_in[4];
  const float* bv  = (const float*)d_in[5];
  const float* Wo  = (const float*)d_in[6];
  const float* bo  = (const float*)d_in[7];
  const float* gm  = (const float*)d_in[8];
  const float* l1g = (const float*)d_in[9];
  const float* l1b = (const float*)d_in[10];
  const float* W1  = (const float*)d_in[11];
  const float* b1  = (const float*)d_in[12];
  const float* W2  = (const float*)d_in[13];
  const float* b2  = (const float*)d_in[14];
  const float* l2g = (const float*)d_in[15];
  const float* l2b = (const float*)d_in[16];

  char* ws = (char*)d_ws;
  u16* WT = (u16*)ws;                              // 17.3 MB packed weights
  u16* A0 = (u16*)(ws + ((size_t)18  << 20));      // 16 MiB bf16 act slots
  u16* A1 = (u16*)(ws + ((size_t)34  << 20));
  u16* A2 = (u16*)(ws + ((size_t)50  << 20));
  u16* A3 = (u16*)(ws + ((size_t)66  << 20));
  float* F0 = (float*)(ws + ((size_t)82  << 20));  // 32 MiB f32 slots
  float* F1 = (float*)(ws + ((size_t)114 << 20));
  u16* Amid = (u16*)(ws + ((size_t)146 << 20));    // 64 MiB FFN mid (if ws allows)
  const bool bigws = ws_size >= ((size_t)211 << 20);

  u16* WkT = WT;                    // [L][512][512]
  u16* WvT = WT + (size_t)3 * 262144;
  u16* WoT = WT + (size_t)6 * 262144;
  u16* W1T = WT + (size_t)9 * 262144;              // [L][2048][512]
  u16* W2T = W1T + (size_t)3 * 1048576;            // [L][512][2048]

  pack_w_t<<<dim3(8, 8, 3),  256, 0, stream>>>(Wk, WkT, 512, 512);
  pack_w_t<<<dim3(8, 8, 3),  256, 0, stream>>>(Wv, WvT, 512, 512);
  pack_w_t<<<dim3(8, 8, 3),  256, 0, stream>>>(Wo, WoT, 512, 512);
  pack_w_t<<<dim3(32, 8, 3), 256, 0, stream>>>(W1, W1T, 512, 2048);
  pack_w_t<<<dim3(8, 32, 3), 256, 0, stream>>>(W2, W2T, 2048, 512);
  pack_flat<<<4096, 256, 0, stream>>>(qa, A0);
  pack_flat<<<4096, 256, 0, stream>>>(qe, A1);

  auto gemm = [&](const u16* A, int lda, const u16* Bt, int ldb, const float* bias,
                  float* outF, u16* outB, int ldc, int M, int N, int K,
                  int relu, int accum) {
    gemm_bf16<<<dim3(N / 128, M / 128, 1), 256, 0, stream>>>(
        A, lda, Bt, ldb, bias, outF, outB, ldc, M, N, K, relu, accum,
        nullptr, nullptr, nullptr, nullptr);
  };
  // fused qk + v projection (z=0: qk, z=1: v)
  auto gemm2 = [&](const u16* Aq, const u16* BtQ, const float* biasQ, u16* outQ,
                   const u16* Av, const u16* BtV, const float* biasV, u16* outV) {
    gemm_bf16<<<dim3(4, 128, 2), 256, 0, stream>>>(
        Aq, 512, BtQ, 512, biasQ, nullptr, outQ, 512, MR, 512, 512, 0, 0,
        Av, BtV, biasV, outV);
  };

  auto layer = [&](int li, const u16* qbf, const float* qf32, const u16* vbf,
                   int excl, int zp, int pos,
                   float* lnF, u16* lnB, u16* midB, float* y2F, u16* y2B) {
    const float* bk_l = bk + (size_t)li * DDIM;
    const float* bv_l = bv + (size_t)li * DDIM;
    const float* bo_l = bo + (size_t)li * DDIM;
    const float* gm_l = gm + (size_t)li * HH;
    const float* g1   = l1g + (size_t)li * DDIM;
    const float* be1  = l1b + (size_t)li * DDIM;
    const float* g2   = l2g + (size_t)li * DDIM;
    const float* be2  = l2b + (size_t)li * DDIM;
    const float* b1_l = b1 + (size_t)li * DFFN;
    const float* b2_l = b2 + (size_t)li * DDIM;
    const u16* WkT_l = WkT + (size_t)li * 262144;
    const u16* WvT_l = WvT + (size_t)li * 262144;
    const u16* WoT_l = WoT + (size_t)li * 262144;
    const u16* W1T_l = W1T + (size_t)li * 1048576;
    const u16* W2T_l = W2T + (size_t)li * 1048576;

    gemm2(qbf, WkT_l, bk_l, A2, vbf, WvT_l, bv_l, A3);
    attn_mfma<<<BB * HH, 512, 0, stream>>>(A2, A3, gm_l, A3, excl, zp);
    gemm(A3, 512, WoT_l, 512, bo_l, F0, nullptr, 512, MR, 512, 512, 0, 0);
    ln_kernel<<<MR / 4, 256, 0, stream>>>(qf32, F0, g1, be1, lnF, lnB);
    if (pos) {
      if (bigws) {
        gemm(lnB, 512, W1T_l, 512, b1_l, nullptr, Amid, DFFN, MR, DFFN, 512, 1, 0);
        gemm(Amid, DFFN, W2T_l, DFFN, b2_l, F0, nullptr, 512, MR, 512, DFFN, 0, 0);
      } else {
        for (int c = 0; c < 4; ++c) {
          gemm(lnB, 512, W1T_l + (size_t)c * 512 * 512, 512, b1_l + c * 512,
               nullptr, midB, 512, MR, 512, 512, 1, 0);
          gemm(midB, 512, W2T_l + (size_t)c * 512, 2048, (c == 0) ? b2_l : nullptr,
               F0, nullptr, 512, MR, 512, 512, 0, (c > 0) ? 1 : 0);
        }
      }
      ln_kernel<<<MR / 4, 256, 0, stream>>>(lnF, F0, g2, be2, y2F, y2B);
    }
  };

  layer(0, A0, qa, A0, 0, 0, 1, F1, A2, A3, nullptr, A0);
  layer(1, A1, qe, A1, 0, 0, 0, F1, A1, nullptr, nullptr, nullptr);
  layer(2, A1, F1, A0, 1, 1, 1, F1, A1, A2, (float*)d_out, nullptr);
}

// Round 7
// 818.788 us; speedup vs baseline: 11.5142x; 1.3204x over previous
//
#include <hip/hip_runtime.h>

#define BB   32
#define SS   512
#define DDIM 512
#define HH   8
#define DFFN 2048
#define MR   (BB*SS)   // 16384 rows

typedef unsigned int   u32;
typedef unsigned short u16;
typedef unsigned char  u8;
typedef __attribute__((ext_vector_type(8))) short bf16x8;
typedef __attribute__((ext_vector_type(4))) float f32x4;

// ---------- bf16 helpers ----------
__device__ __forceinline__ u32 packbf2(float x, float y) {
  u32 ux = __float_as_uint(x), uy = __float_as_uint(y);
  u32 hx = (ux + 0x7FFFu + ((ux >> 16) & 1u)) >> 16;
  u32 hy = (uy + 0x7FFFu + ((uy >> 16) & 1u)) >> 16;
  return hx | (hy << 16);
}
__device__ __forceinline__ u16 pack1bf(float x) {
  u32 u = __float_as_uint(x);
  return (u16)((u + 0x7FFFu + ((u >> 16) & 1u)) >> 16);
}
__device__ __forceinline__ float bf1(u16 h)  { return __uint_as_float(((u32)h) << 16); }

__device__ __forceinline__ float redsum2(float v) {
  v += __shfl_xor(v, 16, 64);
  v += __shfl_xor(v, 32, 64);
  return v;
}
__device__ __forceinline__ float redmax2(float v) {
  v = fmaxf(v, __shfl_xor(v, 16, 64));
  v = fmaxf(v, __shfl_xor(v, 32, 64));
  return v;
}

// ---------- flat f32 -> bf16 pack ----------
__global__ __launch_bounds__(256) void pack_flat(const float* __restrict__ in,
                                                 u16* __restrict__ out) {
  size_t i = ((size_t)blockIdx.x * 256 + threadIdx.x) * 8;
  float4 a = *(const float4*)(in + i);
  float4 b = *(const float4*)(in + i + 4);
  uint4 o;
  o.x = packbf2(a.x, a.y); o.y = packbf2(a.z, a.w);
  o.z = packbf2(b.x, b.y); o.w = packbf2(b.z, b.w);
  *(uint4*)(out + i) = o;
}

// ---------- weight transpose-pack: f32 [K,N] -> bf16 [N,K], gridDim.z = layers ----------
__global__ __launch_bounds__(256) void pack_w_t(const float* __restrict__ in,
                                                u16* __restrict__ out, int K, int N) {
  __shared__ float tile[64][65];
  const int t  = threadIdx.x;
  const int n0 = blockIdx.x * 64, k0 = blockIdx.y * 64;
  in  += (size_t)blockIdx.z * K * N;
  out += (size_t)blockIdx.z * N * K;
  #pragma unroll
  for (int it = 0; it < 4; ++it) {
    int idx = it * 256 + t;
    int kk = idx >> 4, n4 = idx & 15;
    float4 v = *(const float4*)(in + (size_t)(k0 + kk) * N + n0 + n4 * 4);
    tile[kk][n4*4+0] = v.x; tile[kk][n4*4+1] = v.y;
    tile[kk][n4*4+2] = v.z; tile[kk][n4*4+3] = v.w;
  }
  __syncthreads();
  #pragma unroll
  for (int it = 0; it < 4; ++it) {
    int idx = it * 256 + t;
    int nn = idx >> 4, g = idx & 15;
    uint2 o;
    o.x = packbf2(tile[g*4+0][nn], tile[g*4+1][nn]);
    o.y = packbf2(tile[g*4+2][nn], tile[g*4+3][nn]);
    *(uint2*)(out + (size_t)(n0 + nn) * K + k0 + g * 4) = o;
  }
}

// ---------- bf16 MFMA GEMM (XCD-swizzled, optional dual via gridDim.z) ----------
// C[M,N] = A[M,K] @ B[K,N], Bt = B^T stored [N][K].
__global__ __launch_bounds__(256) void gemm_bf16(
    const u16* __restrict__ A, int lda,
    const u16* __restrict__ Bt, int ldb,
    const float* __restrict__ bias,
    float* __restrict__ outF, u16* __restrict__ outB, int ldc,
    int M, int N, int K, int relu, int accum,
    const u16* __restrict__ A2, const u16* __restrict__ Bt2,
    const float* __restrict__ bias2, u16* __restrict__ outB2)
{
  __shared__ u16 sA[128 * 32];  // [row][k], row stride 32
  __shared__ u16 sB[128 * 32];  // [col][k]

  // bijective XCD swizzle (m204): consecutive tiles land on one XCD's L2
  const int nwg  = gridDim.x * gridDim.y;
  const int orig = blockIdx.y * gridDim.x + blockIdx.x;
  const int q8   = nwg >> 3, r8 = nwg & 7;
  const int xcd  = orig & 7, idx8 = orig >> 3;
  const int wg   = (xcd < r8 ? xcd * (q8 + 1) : r8 * (q8 + 1) + (xcd - r8) * q8) + idx8;
  const int bx   = wg % gridDim.x, by = wg / gridDim.x;

  const u16* Ax = A; const u16* Bx = Bt;
  const float* biasx = bias;
  float* outFx = outF; u16* outBx = outB;
  if (blockIdx.z) { Ax = A2; Bx = Bt2; biasx = bias2; outFx = nullptr; outBx = outB2; }

  const int t    = threadIdx.x;
  const int lane = t & 63, wid = t >> 6;
  const int wr   = wid >> 1, wc = wid & 1;
  const int row0 = by * 128, col0 = bx * 128;
  const int kg   = lane >> 4, rl = lane & 15;

  f32x4 acc[4][4] = {};

  for (int k0 = 0; k0 < K; k0 += 32) {
    #pragma unroll
    for (int it = 0; it < 2; ++it) {
      int idx = it * 256 + t;
      int r = idx >> 2, seg = idx & 3;
      const u16* gA = Ax + (size_t)(row0 + r) * lda + k0 + seg * 8;
      const u16* gB = Bx + (size_t)(col0 + r) * ldb + k0 + seg * 8;
      __builtin_amdgcn_global_load_lds(
          (const __attribute__((address_space(1))) u32*)gA,
          (__attribute__((address_space(3))) u32*)(sA + (it * 256 + wid * 64) * 8),
          16, 0, 0);
      __builtin_amdgcn_global_load_lds(
          (const __attribute__((address_space(1))) u32*)gB,
          (__attribute__((address_space(3))) u32*)(sB + (it * 256 + wid * 64) * 8),
          16, 0, 0);
    }
    __syncthreads();
    bf16x8 af[4], bfr[4];
    #pragma unroll
    for (int m = 0; m < 4; ++m)
      af[m] = *(const bf16x8*)(sA + (wr * 64 + m * 16 + rl) * 32 + kg * 8);
    #pragma unroll
    for (int n = 0; n < 4; ++n)
      bfr[n] = *(const bf16x8*)(sB + (wc * 64 + n * 16 + rl) * 32 + kg * 8);
    #pragma unroll
    for (int m = 0; m < 4; ++m)
      #pragma unroll
      for (int n = 0; n < 4; ++n)
        acc[m][n] = __builtin_amdgcn_mfma_f32_16x16x32_bf16(af[m], bfr[n], acc[m][n], 0, 0, 0);
    __syncthreads();
  }

  #pragma unroll
  for (int m = 0; m < 4; ++m) {
    #pragma unroll
    for (int n = 0; n < 4; ++n) {
      const int col = col0 + wc * 64 + n * 16 + rl;
      const float bs = biasx ? biasx[col] : 0.f;
      #pragma unroll
      for (int q = 0; q < 4; ++q) {
        const int row = row0 + wr * 64 + m * 16 + kg * 4 + q;
        float v = acc[m][n][q] + bs;
        if (accum) v += outFx[(size_t)row * ldc + col];
        if (relu)  v = fmaxf(v, 0.f);
        if (outFx) outFx[(size_t)row * ldc + col] = v;
        if (outBx) outBx[(size_t)row * ldc + col] = pack1bf(v);
      }
    }
  }
}

// ---------- MFMA attention with distance-decay rescoring (2-pass streamed) ----------
// Block = (b,h), 512 threads (8 waves). Each wave owns 4 row-tiles of 16 q-rows
// {w, 15-w, 16+w, 31-w}. Swapped QK^T (mfma(K,Q) -> S^T): lane (ql,g) holds
// entries for q-row i0+ql, k = kt*16+4g+rg.
// NO persistent score array (r6 post-mortem: the spilled score array streamed
// through scratch was ~120MB HBM/dispatch = most of the runtime). Instead:
//   pass1: online max+sum (m1, S1) — scores discarded.
//   pass2: recompute scores by MFMA (MFMA is ~2% utilized — free), then
//          e1 -> cumsum -> eff -> s2 -> e2 = exp(s2 - max(m1,0)) [defer-max:
//          eff<=1 so s2 <= max(m1,0); bf16 e2 has f32 exponent range] packed
//          straight into the PV MFMA. O scaled by 1/S2 at the end (PV linear).
__global__ __attribute__((amdgpu_flat_work_group_size(512, 512)))
           __attribute__((amdgpu_waves_per_eu(1, 2)))
void attn_mfma(
    const u16* __restrict__ qk, const u16* __restrict__ vbuf,
    const float* __restrict__ gam, u16* __restrict__ out,
    int mask_excl, int zero_pad)
{
  __shared__ __align__(16) u8 kSb[65536];  // K/Q rows [512][64] bf16, byte ^= (row&7)<<4
  __shared__ __align__(16) u8 vTb[65536];  // V^T [64 d][512 k] bf16, byte ^= ((d&7)^((d>>3)&7))<<4
  __shared__ __align__(16) u8 pChb[8192];  // per-wave 1KB P chunk buffers

  const int t    = threadIdx.x;
  const int lane = t & 63, wid = t >> 6;
  const int ql   = lane & 15, g = lane >> 4;
  const int bh   = blockIdx.x, b = bh >> 3, h = bh & 7;
  const size_t base = (size_t)b * SS * DDIM + (size_t)h * 64;

  float gv = gam[h];
  float sp = (gv > 0.f) ? (gv + log1pf(__expf(-gv))) : log1pf(__expf(gv));
  const float gamma = -sp;

  // ---- stage K/Q ----
  for (int it = 0; it < 8; ++it) {
    int idx = it * 512 + t;
    int j = idx >> 3, u = idx & 7;
    uint4 w = *(const uint4*)(qk + base + (size_t)j * DDIM + u * 8);
    *(uint4*)(kSb + ((j * 128 + u * 16) ^ ((j & 7) << 4))) = w;
  }
  // ---- stage V^T: STATIC dd (no dynamic union index -> no scratch, rule #20);
  //      swizzle ((d&7)^((d>>3)&7))<<4 = (dd^u)<<4 spreads the u16 scatter
  //      across all 32 banks (write side) and keeps PV b128 reads at floor ----
  for (int it = 0; it < 8; ++it) {
    int idx = it * 512 + t;
    int j = idx >> 3, u = idx & 7;
    union { uint4 v4; u16 s[8]; } uu;
    uu.v4 = *(const uint4*)(vbuf + base + (size_t)j * DDIM + u * 8);
    #pragma unroll
    for (int dd = 0; dd < 8; ++dd) {
      int d = u * 8 + dd;
      *(u16*)(vTb + d * 1024 + ((2 * j) ^ ((dd ^ u) << 4))) = uu.s[dd];
    }
  }
  __syncthreads();

  // diagonal-tile validity per (g, reg): k_local = 4g+rg vs q_local = ql
  bool vm[4];
  #pragma unroll
  for (int rg = 0; rg < 4; ++rg) {
    int kl = 4 * g + rg;
    vm[rg] = mask_excl ? (kl < ql) : (kl <= ql);
  }

  u8* pB = pChb + wid * 1024;
  const int swp = (ql & 3) << 4;

  // per-lane V read constants: d = n*16 + ql
  int vbase[4], vsw[4];
  #pragma unroll
  for (int n = 0; n < 4; ++n) {
    int d = n * 16 + ql;
    vbase[n] = d * 1024;
    vsw[n]   = ((d & 7) ^ ((d >> 3) & 7)) << 4;
  }

  #pragma unroll
  for (int ri = 0; ri < 4; ++ri) {
    int r0_ = (ri == 0) ? wid : (ri == 1) ? (15 - wid) : (ri == 2) ? (16 + wid) : (31 - wid);
    const int rs = __builtin_amdgcn_readfirstlane(r0_);
    const int i0 = rs * 16;

    const int qrow = i0 + ql;
    const int qsw  = (qrow & 7) << 4;
    bf16x8 qf0 = *(const bf16x8*)(kSb + ((qrow * 128      + g * 16) ^ qsw));
    bf16x8 qf1 = *(const bf16x8*)(kSb + ((qrow * 128 + 64 + g * 16) ^ qsw));

    // ---- pass 1: online softmax-1 stats (m1, S1), scores discarded ----
    float mrun = -3.0e38f, Srun = 0.f;
    #pragma unroll
    for (int kt = 0; kt < 32; ++kt) {
      if (kt <= rs) {
        const bool dg = (kt == rs);
        const int krow = kt * 16 + ql;
        const int ksw  = (krow & 7) << 4;
        bf16x8 ka0 = *(const bf16x8*)(kSb + ((krow * 128      + g * 16) ^ ksw));
        bf16x8 ka1 = *(const bf16x8*)(kSb + ((krow * 128 + 64 + g * 16) ^ ksw));
        f32x4 dv = {};
        dv = __builtin_amdgcn_mfma_f32_16x16x32_bf16(ka0, qf0, dv, 0, 0, 0);
        dv = __builtin_amdgcn_mfma_f32_16x16x32_bf16(ka1, qf1, dv, 0, 0, 0);
        float s0 = dv[0] * 0.125f, s1 = dv[1] * 0.125f;
        float s2 = dv[2] * 0.125f, s3 = dv[3] * 0.125f;
        const bool v0 = !dg || vm[0], v1 = !dg || vm[1];
        const bool v2 = !dg || vm[2], v3 = !dg || vm[3];
        float kmax = fmaxf(fmaxf(v0 ? s0 : -3.0e38f, v1 ? s1 : -3.0e38f),
                           fmaxf(v2 ? s2 : -3.0e38f, v3 ? s3 : -3.0e38f));
        float nm = fmaxf(mrun, kmax);
        Srun *= __expf(mrun - nm);
        float e0 = v0 ? __expf(s0 - nm) : 0.f;
        float e1 = v1 ? __expf(s1 - nm) : 0.f;
        float e2 = v2 ? __expf(s2 - nm) : 0.f;
        float e3 = v3 ? __expf(s3 - nm) : 0.f;
        Srun += (e0 + e1) + (e2 + e3);
        mrun = nm;
      }
    }
    const float m1 = redmax2(mrun);
    const float S1 = redsum2(Srun * __expf(mrun - m1));
    const float inv1 = (S1 > 0.f) ? (1.f / S1) : 0.f;
    const float M2p  = fmaxf(m1, 0.f);

    // ---- pass 2: streamed recompute -> cumsum -> rescore -> PV ----
    f32x4 oacc[4] = {};
    float cbase = 0.f, S2l = 0.f;
    const float qlf = (float)(i0 + ql);

    auto subkt = [&](int kt, bool dg, u32& wA, u32& wB) {
      const int krow = kt * 16 + ql;
      const int ksw  = (krow & 7) << 4;
      bf16x8 ka0 = *(const bf16x8*)(kSb + ((krow * 128      + g * 16) ^ ksw));
      bf16x8 ka1 = *(const bf16x8*)(kSb + ((krow * 128 + 64 + g * 16) ^ ksw));
      f32x4 dv = {};
      dv = __builtin_amdgcn_mfma_f32_16x16x32_bf16(ka0, qf0, dv, 0, 0, 0);
      dv = __builtin_amdgcn_mfma_f32_16x16x32_bf16(ka1, qf1, dv, 0, 0, 0);
      float sv[4];
      sv[0] = dv[0] * 0.125f; sv[1] = dv[1] * 0.125f;
      sv[2] = dv[2] * 0.125f; sv[3] = dv[3] * 0.125f;
      const bool v0 = !dg || vm[0], v1 = !dg || vm[1];
      const bool v2 = !dg || vm[2], v3 = !dg || vm[3];
      float e0 = v0 ? __expf(sv[0] - m1) : 0.f;
      float e1 = v1 ? __expf(sv[1] - m1) : 0.f;
      float e2 = v2 ? __expf(sv[2] - m1) : 0.f;
      float e3 = v3 ? __expf(sv[3] - m1) : 0.f;
      float p0 = e0, p1 = p0 + e1, p2 = p1 + e2, p3 = p2 + e3;
      float a16 = __shfl_up(p3, 16, 64);
      float a32 = __shfl_up(p3, 32, 64);
      float a48 = __shfl_up(p3, 48, 64);
      float gp = (g >= 1 ? a16 : 0.f) + (g >= 2 ? a32 : 0.f) + (g >= 3 ? a48 : 0.f);
      float tt = __shfl(gp + p3, ql + 48, 64);
      const float pbase = cbase + gp;
      const float pf = qlf - (float)(kt * 16 + 4 * g);
      float ipr[4] = {p0, p1, p2, p3};
      bool  vv[4]  = {v0, v1, v2, v3};
      float q2[4];
      #pragma unroll
      for (int rg = 0; rg < 4; ++rg) {
        float rem  = fmaxf((S1 - (pbase + ipr[rg])) * inv1, 0.f);
        float pos  = pf - (float)rg;
        float dist = sqrtf(fmaxf(rem * pos, 0.f));
        float eff  = fmaxf(__expf(gamma * dist), 1e-5f);  // eff <= 1 (gamma <= 0)
        float s2v  = sv[rg] * eff;
        float ee   = vv[rg] ? __expf(s2v - M2p) : 0.f;
        q2[rg] = ee;
        S2l += ee;
      }
      wA = packbf2(q2[0], q2[1]);
      wB = packbf2(q2[2], q2[3]);
      cbase += tt;
    };

    #pragma unroll
    for (int c = 0; c < 16; ++c) {
      if (2 * c <= rs) {
        u32 w0 = 0, w1 = 0, w2 = 0, w3 = 0;
        subkt(2 * c, (2 * c == rs), w0, w1);
        if (2 * c + 1 <= rs) subkt(2 * c + 1, (2 * c + 1 == rs), w2, w3);
        *(u32*)(pB + ((ql * 64 +      8 * g    ) ^ swp)) = w0;
        *(u32*)(pB + ((ql * 64 +      8 * g + 4) ^ swp)) = w1;
        *(u32*)(pB + ((ql * 64 + 32 + 8 * g    ) ^ swp)) = w2;
        *(u32*)(pB + ((ql * 64 + 32 + 8 * g + 4) ^ swp)) = w3;
        bf16x8 pa = *(const bf16x8*)(pB + ((ql * 64 + 16 * g) ^ swp));
        #pragma unroll
        for (int n = 0; n < 4; ++n) {
          bf16x8 vb = *(const bf16x8*)(vTb + vbase[n] + ((64 * c + 16 * g) ^ vsw[n]));
          oacc[n] = __builtin_amdgcn_mfma_f32_16x16x32_bf16(pa, vb, oacc[n], 0, 0, 0);
        }
      }
    }

    const float S2   = redsum2(S2l);
    const float inv2 = 1.f / fmaxf(S2, 1e-30f);
    float i2[4];
    #pragma unroll
    for (int rg = 0; rg < 4; ++rg) i2[rg] = __shfl(inv2, 4 * g + rg, 64);

    // ---- store O tile: q_out = i0 + 4g + rg, d = n*16 + ql ----
    #pragma unroll
    for (int n = 0; n < 4; ++n) {
      #pragma unroll
      for (int rg = 0; rg < 4; ++rg) {
        const int qo = i0 + 4 * g + rg;
        float val = oacc[n][rg] * i2[rg];
        if (zero_pad && qo == 0) val = 0.f;
        out[base + (size_t)qo * DDIM + n * 16 + ql] = pack1bf(val);
      }
    }
  }
}

// ---------- fused residual + LayerNorm (dual f32/bf16 out) ----------
__global__ __launch_bounds__(256) void ln_kernel(
    const float* __restrict__ a, const float* __restrict__ bsrc,
    const float* __restrict__ g, const float* __restrict__ be,
    float* __restrict__ outF, u16* __restrict__ outB)
{
  const int lane = threadIdx.x & 63, w = threadIdx.x >> 6;
  const size_t row = (size_t)blockIdx.x * 4 + w;
  const float* pa = a    + row * DDIM;
  const float* pb = bsrc + row * DDIM;
  float v[8];
  float sum = 0.f;
  #pragma unroll
  for (int c = 0; c < 2; ++c) {
    float4 va = *(const float4*)(pa + c * 256 + lane * 4);
    float4 vb = *(const float4*)(pb + c * 256 + lane * 4);
    v[c*4+0] = va.x + vb.x; v[c*4+1] = va.y + vb.y;
    v[c*4+2] = va.z + vb.z; v[c*4+3] = va.w + vb.w;
    sum += v[c*4+0] + v[c*4+1] + v[c*4+2] + v[c*4+3];
  }
  #pragma unroll
  for (int off = 32; off > 0; off >>= 1) sum += __shfl_xor(sum, off, 64);
  const float mean = sum * (1.f / 512.f);
  float var = 0.f;
  #pragma unroll
  for (int k = 0; k < 8; ++k) { float dd = v[k] - mean; var = fmaf(dd, dd, var); }
  #pragma unroll
  for (int off = 32; off > 0; off >>= 1) var += __shfl_xor(var, off, 64);
  var *= (1.f / 512.f);
  const float inv = rsqrtf(var + 1e-5f);
  #pragma unroll
  for (int c = 0; c < 2; ++c) {
    float4 gg = *(const float4*)(g  + c * 256 + lane * 4);
    float4 bb = *(const float4*)(be + c * 256 + lane * 4);
    float4 o;
    o.x = (v[c*4+0] - mean) * inv * gg.x + bb.x;
    o.y = (v[c*4+1] - mean) * inv * gg.y + bb.y;
    o.z = (v[c*4+2] - mean) * inv * gg.z + bb.z;
    o.w = (v[c*4+3] - mean) * inv * gg.w + bb.w;
    const size_t off4 = row * DDIM + c * 256 + lane * 4;
    if (outF) *(float4*)(outF + off4) = o;
    if (outB) {
      uint2 p;
      p.x = packbf2(o.x, o.y); p.y = packbf2(o.z, o.w);
      *(uint2*)(outB + off4) = p;
    }
  }
}

// ---------- orchestration ----------
extern "C" void kernel_launch(void* const* d_in, const int* in_sizes, int n_in,
                              void* d_out, int out_size, void* d_ws, size_t ws_size,
                              hipStream_t stream) {
  const float* qe  = (const float*)d_in[0];
  const float* qa  = (const float*)d_in[1];
  const float* Wk  = (const float*)d_in[2];
  const float* bk  = (const float*)d_in[3];
  const float* Wv  = (const float*)d_in[4];
  const float* bv  = (const float*)d_in[5];
  const float* Wo  = (const float*)d_in[6];
  const float* bo  = (const float*)d_in[7];
  const float* gm  = (const float*)d_in[8];
  const float* l1g = (const float*)d_in[9];
  const float* l1b = (const float*)d_in[10];
  const float* W1  = (const float*)d_in[11];
  const float* b1  = (const float*)d_in[12];
  const float* W2  = (const float*)d_in[13];
  const float* b2  = (const float*)d_in[14];
  const float* l2g = (const float*)d_in[15];
  const float* l2b = (const float*)d_in[16];

  char* ws = (char*)d_ws;
  u16* WT = (u16*)ws;                              // 17.3 MB packed weights
  u16* A0 = (u16*)(ws + ((size_t)18  << 20));      // 16 MiB bf16 act slots
  u16* A1 = (u16*)(ws + ((size_t)34  << 20));
  u16* A2 = (u16*)(ws + ((size_t)50  << 20));
  u16* A3 = (u16*)(ws + ((size_t)66  << 20));
  float* F0 = (float*)(ws + ((size_t)82  << 20));  // 32 MiB f32 slots
  float* F1 = (float*)(ws + ((size_t)114 << 20));
  u16* Amid = (u16*)(ws + ((size_t)146 << 20));    // 64 MiB FFN mid (if ws allows)
  const bool bigws = ws_size >= ((size_t)211 << 20);

  u16* WkT = WT;                    // [L][512][512]
  u16* WvT = WT + (size_t)3 * 262144;
  u16* WoT = WT + (size_t)6 * 262144;
  u16* W1T = WT + (size_t)9 * 262144;              // [L][2048][512]
  u16* W2T = W1T + (size_t)3 * 1048576;            // [L][512][2048]

  pack_w_t<<<dim3(8, 8, 3),  256, 0, stream>>>(Wk, WkT, 512, 512);
  pack_w_t<<<dim3(8, 8, 3),  256, 0, stream>>>(Wv, WvT, 512, 512);
  pack_w_t<<<dim3(8, 8, 3),  256, 0, stream>>>(Wo, WoT, 512, 512);
  pack_w_t<<<dim3(32, 8, 3), 256, 0, stream>>>(W1, W1T, 512, 2048);
  pack_w_t<<<dim3(8, 32, 3), 256, 0, stream>>>(W2, W2T, 2048, 512);
  pack_flat<<<4096, 256, 0, stream>>>(qa, A0);
  pack_flat<<<4096, 256, 0, stream>>>(qe, A1);

  auto gemm = [&](const u16* A, int lda, const u16* Bt, int ldb, const float* bias,
                  float* outF, u16* outB, int ldc, int M, int N, int K,
                  int relu, int accum) {
    gemm_bf16<<<dim3(N / 128, M / 128, 1), 256, 0, stream>>>(
        A, lda, Bt, ldb, bias, outF, outB, ldc, M, N, K, relu, accum,
        nullptr, nullptr, nullptr, nullptr);
  };
  // fused qk + v projection (z=0: qk, z=1: v)
  auto gemm2 = [&](const u16* Aq, const u16* BtQ, const float* biasQ, u16* outQ,
                   const u16* Av, const u16* BtV, const float* biasV, u16* outV) {
    gemm_bf16<<<dim3(4, 128, 2), 256, 0, stream>>>(
        Aq, 512, BtQ, 512, biasQ, nullptr, outQ, 512, MR, 512, 512, 0, 0,
        Av, BtV, biasV, outV);
  };

  auto layer = [&](int li, const u16* qbf, const float* qf32, const u16* vbf,
                   int excl, int zp, int pos,
                   float* lnF, u16* lnB, u16* midB, float* y2F, u16* y2B) {
    const float* bk_l = bk + (size_t)li * DDIM;
    const float* bv_l = bv + (size_t)li * DDIM;
    const float* bo_l = bo + (size_t)li * DDIM;
    const float* gm_l = gm + (size_t)li * HH;
    const float* g1   = l1g + (size_t)li * DDIM;
    const float* be1  = l1b + (size_t)li * DDIM;
    const float* g2   = l2g + (size_t)li * DDIM;
    const float* be2  = l2b + (size_t)li * DDIM;
    const float* b1_l = b1 + (size_t)li * DFFN;
    const float* b2_l = b2 + (size_t)li * DDIM;
    const u16* WkT_l = WkT + (size_t)li * 262144;
    const u16* WvT_l = WvT + (size_t)li * 262144;
    const u16* WoT_l = WoT + (size_t)li * 262144;
    const u16* W1T_l = W1T + (size_t)li * 1048576;
    const u16* W2T_l = W2T + (size_t)li * 1048576;

    gemm2(qbf, WkT_l, bk_l, A2, vbf, WvT_l, bv_l, A3);
    attn_mfma<<<BB * HH, 512, 0, stream>>>(A2, A3, gm_l, A3, excl, zp);
    gemm(A3, 512, WoT_l, 512, bo_l, F0, nullptr, 512, MR, 512, 512, 0, 0);
    ln_kernel<<<MR / 4, 256, 0, stream>>>(qf32, F0, g1, be1, lnF, lnB);
    if (pos) {
      if (bigws) {
        gemm(lnB, 512, W1T_l, 512, b1_l, nullptr, Amid, DFFN, MR, DFFN, 512, 1, 0);
        gemm(Amid, DFFN, W2T_l, DFFN, b2_l, F0, nullptr, 512, MR, 512, DFFN, 0, 0);
      } else {
        for (int c = 0; c < 4; ++c) {
          gemm(lnB, 512, W1T_l + (size_t)c * 512 * 512, 512, b1_l + c * 512,
               nullptr, midB, 512, MR, 512, 512, 1, 0);
          gemm(midB, 512, W2T_l + (size_t)c * 512, 2048, (c == 0) ? b2_l : nullptr,
               F0, nullptr, 512, MR, 512, 512, 0, (c > 0) ? 1 : 0);
        }
      }
      ln_kernel<<<MR / 4, 256, 0, stream>>>(lnF, F0, g2, be2, y2F, y2B);
    }
  };

  layer(0, A0, qa, A0, 0, 0, 1, F1, A2, A3, nullptr, A0);
  layer(1, A1, qe, A1, 0, 0, 0, F1, A1, nullptr, nullptr, nullptr);
  layer(2, A1, F1, A0, 1, 1, 1, F1, A1, A2, (float*)d_out, nullptr);
}

// Round 8
// 742.211 us; speedup vs baseline: 12.7021x; 1.1032x over previous
//
#include <hip/hip_runtime.h>

#define BB   32
#define SS   512
#define DDIM 512
#define HH   8
#define DFFN 2048
#define MR   (BB*SS)   // 16384 rows

typedef unsigned int   u32;
typedef unsigned short u16;
typedef unsigned char  u8;
typedef __attribute__((ext_vector_type(8))) short bf16x8;
typedef __attribute__((ext_vector_type(4))) float f32x4;

// ---------- bf16 helpers ----------
__device__ __forceinline__ u32 packbf2(float x, float y) {
  u32 ux = __float_as_uint(x), uy = __float_as_uint(y);
  u32 hx = (ux + 0x7FFFu + ((ux >> 16) & 1u)) >> 16;
  u32 hy = (uy + 0x7FFFu + ((uy >> 16) & 1u)) >> 16;
  return hx | (hy << 16);
}
__device__ __forceinline__ u16 pack1bf(float x) {
  u32 u = __float_as_uint(x);
  return (u16)((u + 0x7FFFu + ((u >> 16) & 1u)) >> 16);
}
__device__ __forceinline__ float bf1(u16 h)  { return __uint_as_float(((u32)h) << 16); }

__device__ __forceinline__ float redsum2(float v) {
  v += __shfl_xor(v, 16, 64);
  v += __shfl_xor(v, 32, 64);
  return v;
}
__device__ __forceinline__ float redmax2(float v) {
  v = fmaxf(v, __shfl_xor(v, 16, 64));
  v = fmaxf(v, __shfl_xor(v, 32, 64));
  return v;
}

// ---------- flat f32 -> bf16 pack ----------
__global__ __launch_bounds__(256) void pack_flat(const float* __restrict__ in,
                                                 u16* __restrict__ out) {
  size_t i = ((size_t)blockIdx.x * 256 + threadIdx.x) * 8;
  float4 a = *(const float4*)(in + i);
  float4 b = *(const float4*)(in + i + 4);
  uint4 o;
  o.x = packbf2(a.x, a.y); o.y = packbf2(a.z, a.w);
  o.z = packbf2(b.x, b.y); o.w = packbf2(b.z, b.w);
  *(uint4*)(out + i) = o;
}

// ---------- weight transpose-pack: f32 [K,N] -> bf16 [N,K], gridDim.z = layers ----------
__global__ __launch_bounds__(256) void pack_w_t(const float* __restrict__ in,
                                                u16* __restrict__ out, int K, int N) {
  __shared__ float tile[64][65];
  const int t  = threadIdx.x;
  const int n0 = blockIdx.x * 64, k0 = blockIdx.y * 64;
  in  += (size_t)blockIdx.z * K * N;
  out += (size_t)blockIdx.z * N * K;
  #pragma unroll
  for (int it = 0; it < 4; ++it) {
    int idx = it * 256 + t;
    int kk = idx >> 4, n4 = idx & 15;
    float4 v = *(const float4*)(in + (size_t)(k0 + kk) * N + n0 + n4 * 4);
    tile[kk][n4*4+0] = v.x; tile[kk][n4*4+1] = v.y;
    tile[kk][n4*4+2] = v.z; tile[kk][n4*4+3] = v.w;
  }
  __syncthreads();
  #pragma unroll
  for (int it = 0; it < 4; ++it) {
    int idx = it * 256 + t;
    int nn = idx >> 4, g = idx & 15;
    uint2 o;
    o.x = packbf2(tile[g*4+0][nn], tile[g*4+1][nn]);
    o.y = packbf2(tile[g*4+2][nn], tile[g*4+3][nn]);
    *(uint2*)(out + (size_t)(n0 + nn) * K + k0 + g * 4) = o;
  }
}

// ---------- 256x256 8-phase bf16 MFMA GEMM (m201-style port, plain HIP) ----------
// C[M,N] = A[M,K] @ B[K,N], Bt = B^T stored [N][K] bf16.
// 8 waves (2 wm x 4 wn), per-wave 128x64 out, BK=64, LDS 128KB = 2 bufs x
// {A-half0/1, B-half0/1} of 16KB. A-half h = rows with bit6==h (per-wm split);
// B-half h = cols with bit5==h (per-wn split). Phase = one C-quadrant (mh,nh)
// x full K=64 (16 MFMA) + 12 swizzled ds_read_b128 + 1 half-tile prefetch +
// raw s_barrier (no vmcnt drain). Counted vmcnt(4) only at phases 4 & 8.
// LDS XOR-swizzle (s&7)<<4 applied on both sides (pre-swizzled global source
// for global_load_lds linear dest + swizzled ds_read addr).
// z: two independent pointer sets (dual-GEMM batching or split-K halves).
__global__ __launch_bounds__(512, 2) void gemm8(
    const u16* __restrict__ Aa, const u16* __restrict__ Ab, int lda,
    const u16* __restrict__ Ba, const u16* __restrict__ Bb, int ldb,
    const float* __restrict__ biasa, const float* __restrict__ biasb,
    float* __restrict__ outFa, float* __restrict__ outFb,
    u16* __restrict__ outBa, u16* __restrict__ outBb,
    int ldc, int Kz, int relu)
{
  __shared__ __align__(16) u8 lds[131072];

  const int z = blockIdx.z;
  const u16* A    = z ? Ab : Aa;
  const u16* Bt   = z ? Bb : Ba;
  const float* bias = z ? biasb : biasa;
  float* outF = z ? outFb : outFa;
  u16*   outB = z ? outBb : outBa;

  // bijective XCD swizzle on the x-y plane (m204)
  const int nwg  = gridDim.x * gridDim.y;
  const int orig = blockIdx.y * gridDim.x + blockIdx.x;
  const int q8   = nwg >> 3, r8 = nwg & 7;
  const int xcd  = orig & 7, idx8 = orig >> 3;
  const int wg   = (xcd < r8 ? xcd * (q8 + 1) : r8 * (q8 + 1) + (xcd - r8) * q8) + idx8;
  const int bx   = wg % gridDim.x, by = wg / gridDim.x;
  const int row0 = by * 256, col0 = bx * 256;

  const int t    = threadIdx.x;
  const int lane = t & 63, wid = t >> 6;
  const int wm   = wid >> 2, wn = wid & 3;
  const int rl   = lane & 15, kg = lane >> 4;

  const int NT = Kz >> 6;   // K-tiles of 64 (always even, >= 4 here)

  f32x4 acc[8][4] = {};

  // ---- staging: half-tile = 16KB = 512 thr x 2 x 16B. Linear LDS dest,
  //      pre-swizzled global source (swizzle: kb ^= (s&7)<<4). ----
  auto stageA = [&](int buf, int h, int kt) {
    #pragma unroll
    for (int l = 0; l < 2; ++l) {
      int s  = (l * 512 + t) >> 3;
      int kb = ((lane & 7) * 16) ^ ((s & 7) << 4);
      int row = row0 + ((s >> 6) * 128) + h * 64 + (s & 63);
      const u8* src = (const u8*)A + (size_t)row * lda * 2 + (size_t)kt * 128 + kb;
      u8* dst = lds + buf * 65536 + h * 16384 + (l * 512 + wid * 64) * 16;
      __builtin_amdgcn_global_load_lds(
          (const __attribute__((address_space(1))) u32*)src,
          (__attribute__((address_space(3))) u32*)dst, 16, 0, 0);
    }
  };
  auto stageB = [&](int buf, int h, int kt) {
    #pragma unroll
    for (int l = 0; l < 2; ++l) {
      int s  = (l * 512 + t) >> 3;
      int kb = ((lane & 7) * 16) ^ ((s & 7) << 4);
      int col = col0 + ((s >> 5) * 64) + h * 32 + (s & 31);
      const u8* src = (const u8*)Bt + (size_t)col * ldb * 2 + (size_t)kt * 128 + kb;
      u8* dst = lds + buf * 65536 + 32768 + h * 16384 + (l * 512 + wid * 64) * 16;
      __builtin_amdgcn_global_load_lds(
          (const __attribute__((address_space(1))) u32*)src,
          (__attribute__((address_space(3))) u32*)dst, 16, 0, 0);
    }
  };

  auto rdA = [&](int buf, int mh, int m, int ks) -> bf16x8 {
    int s = wm * 64 + m * 16 + rl;
    int off = buf * 65536 + mh * 16384 + s * 128 + (((ks * 32 + kg * 8) * 2) ^ ((s & 7) << 4));
    return *(const bf16x8*)(lds + off);
  };
  auto rdB = [&](int buf, int nh, int n, int ks) -> bf16x8 {
    int s = wn * 32 + n * 16 + rl;
    int off = buf * 65536 + 32768 + nh * 16384 + s * 128 + (((ks * 32 + kg * 8) * 2) ^ ((s & 7) << 4));
    return *(const bf16x8*)(lds + off);
  };

#define GBAR asm volatile("s_barrier" ::: "memory")
#define VMW4 asm volatile("s_waitcnt vmcnt(4)" ::: "memory")

#define PHASE(BUF, MH, NH, STAGECODE, DOVM) do {                               \
    bf16x8 af_[4][2], bf_[2][2];                                               \
    _Pragma("unroll") for (int m_ = 0; m_ < 4; ++m_)                           \
      _Pragma("unroll") for (int k_ = 0; k_ < 2; ++k_)                         \
        af_[m_][k_] = rdA(BUF, MH, m_, k_);                                    \
    _Pragma("unroll") for (int n_ = 0; n_ < 2; ++n_)                           \
      _Pragma("unroll") for (int k_ = 0; k_ < 2; ++k_)                         \
        bf_[n_][k_] = rdB(BUF, NH, n_, k_);                                    \
    STAGECODE;                                                                 \
    if (DOVM) VMW4;                                                            \
    GBAR;                                                                      \
    __builtin_amdgcn_s_setprio(1);                                             \
    _Pragma("unroll") for (int m_ = 0; m_ < 4; ++m_)                           \
      _Pragma("unroll") for (int n_ = 0; n_ < 2; ++n_) {                       \
        acc[(MH)*4+m_][(NH)*2+n_] = __builtin_amdgcn_mfma_f32_16x16x32_bf16(   \
            af_[m_][0], bf_[n_][0], acc[(MH)*4+m_][(NH)*2+n_], 0, 0, 0);       \
        acc[(MH)*4+m_][(NH)*2+n_] = __builtin_amdgcn_mfma_f32_16x16x32_bf16(   \
            af_[m_][1], bf_[n_][1], acc[(MH)*4+m_][(NH)*2+n_], 0, 0, 0);       \
      }                                                                        \
    __builtin_amdgcn_s_setprio(0);                                             \
    GBAR;                                                                      \
  } while (0)

  // ---- prologue: tile0 fully + tile1's A0,B0 (12 loads); allow last 4 ----
  stageA(0, 0, 0); stageB(0, 0, 0); stageA(0, 1, 0); stageB(0, 1, 0);
  stageA(1, 0, 1); stageB(1, 0, 1);
  VMW4; GBAR;

  for (int i = 0; i < (NT >> 1); ++i) {
    const int T1 = 2 * i + 1;
    int T2 = 2 * i + 2; if (T2 >= NT) T2 -= NT;   // wrap: redundant reload, keeps
    int T3 = 2 * i + 3; if (T3 >= NT) T3 -= NT;   // static vmcnt counts valid
    PHASE(0, 0, 0, stageA(1, 1, T1), 0);
    PHASE(0, 0, 1, stageB(1, 1, T1), 0);
    PHASE(0, 1, 0, stageA(0, 0, T2), 0);
    PHASE(0, 1, 1, stageB(0, 0, T2), 1);
    PHASE(1, 0, 0, stageA(0, 1, T2), 0);
    PHASE(1, 0, 1, stageB(0, 1, T2), 0);
    PHASE(1, 1, 0, stageA(1, 0, T3), 0);
    PHASE(1, 1, 1, stageB(1, 0, T3), 1);
  }
#undef PHASE
#undef GBAR
#undef VMW4

  // ---- epilogue ----
  #pragma unroll
  for (int M = 0; M < 8; ++M) {
    #pragma unroll
    for (int N2 = 0; N2 < 4; ++N2) {
      const int col = col0 + wn * 64 + N2 * 16 + rl;
      const float bs = bias ? bias[col] : 0.f;
      #pragma unroll
      for (int q = 0; q < 4; ++q) {
        const int row = row0 + wm * 128 + M * 16 + kg * 4 + q;
        float v = acc[M][N2][q] + bs;
        if (relu) v = fmaxf(v, 0.f);
        if (outF) outF[(size_t)row * ldc + col] = v;
        if (outB) outB[(size_t)row * ldc + col] = pack1bf(v);
      }
    }
  }
}

// ---------- MFMA attention with distance-decay rescoring (2-pass streamed) ----------
__global__ __attribute__((amdgpu_flat_work_group_size(512, 512)))
           __attribute__((amdgpu_waves_per_eu(1, 2)))
void attn_mfma(
    const u16* __restrict__ qk, const u16* __restrict__ vbuf,
    const float* __restrict__ gam, u16* __restrict__ out,
    int mask_excl, int zero_pad)
{
  __shared__ __align__(16) u8 kSb[65536];  // K/Q rows [512][64] bf16, byte ^= (row&7)<<4
  __shared__ __align__(16) u8 vTb[65536];  // V^T [64 d][512 k] bf16, byte ^= ((d&7)^((d>>3)&7))<<4
  __shared__ __align__(16) u8 pChb[8192];  // per-wave 1KB P chunk buffers

  const int t    = threadIdx.x;
  const int lane = t & 63, wid = t >> 6;
  const int ql   = lane & 15, g = lane >> 4;
  const int bh   = blockIdx.x, b = bh >> 3, h = bh & 7;
  const size_t base = (size_t)b * SS * DDIM + (size_t)h * 64;

  float gv = gam[h];
  float sp = (gv > 0.f) ? (gv + log1pf(__expf(-gv))) : log1pf(__expf(gv));
  const float gamma = -sp;

  for (int it = 0; it < 8; ++it) {
    int idx = it * 512 + t;
    int j = idx >> 3, u = idx & 7;
    uint4 w = *(const uint4*)(qk + base + (size_t)j * DDIM + u * 8);
    *(uint4*)(kSb + ((j * 128 + u * 16) ^ ((j & 7) << 4))) = w;
  }
  for (int it = 0; it < 8; ++it) {
    int idx = it * 512 + t;
    int j = idx >> 3, u = idx & 7;
    union { uint4 v4; u16 s[8]; } uu;
    uu.v4 = *(const uint4*)(vbuf + base + (size_t)j * DDIM + u * 8);
    #pragma unroll
    for (int dd = 0; dd < 8; ++dd) {
      int d = u * 8 + dd;
      *(u16*)(vTb + d * 1024 + ((2 * j) ^ ((dd ^ u) << 4))) = uu.s[dd];
    }
  }
  __syncthreads();

  bool vm[4];
  #pragma unroll
  for (int rg = 0; rg < 4; ++rg) {
    int kl = 4 * g + rg;
    vm[rg] = mask_excl ? (kl < ql) : (kl <= ql);
  }

  u8* pB = pChb + wid * 1024;
  const int swp = (ql & 3) << 4;

  int vbase[4], vsw[4];
  #pragma unroll
  for (int n = 0; n < 4; ++n) {
    int d = n * 16 + ql;
    vbase[n] = d * 1024;
    vsw[n]   = ((d & 7) ^ ((d >> 3) & 7)) << 4;
  }

  #pragma unroll
  for (int ri = 0; ri < 4; ++ri) {
    int r0_ = (ri == 0) ? wid : (ri == 1) ? (15 - wid) : (ri == 2) ? (16 + wid) : (31 - wid);
    const int rs = __builtin_amdgcn_readfirstlane(r0_);
    const int i0 = rs * 16;

    const int qrow = i0 + ql;
    const int qsw  = (qrow & 7) << 4;
    bf16x8 qf0 = *(const bf16x8*)(kSb + ((qrow * 128      + g * 16) ^ qsw));
    bf16x8 qf1 = *(const bf16x8*)(kSb + ((qrow * 128 + 64 + g * 16) ^ qsw));

    float mrun = -3.0e38f, Srun = 0.f;
    #pragma unroll
    for (int kt = 0; kt < 32; ++kt) {
      if (kt <= rs) {
        const bool dg = (kt == rs);
        const int krow = kt * 16 + ql;
        const int ksw  = (krow & 7) << 4;
        bf16x8 ka0 = *(const bf16x8*)(kSb + ((krow * 128      + g * 16) ^ ksw));
        bf16x8 ka1 = *(const bf16x8*)(kSb + ((krow * 128 + 64 + g * 16) ^ ksw));
        f32x4 dv = {};
        dv = __builtin_amdgcn_mfma_f32_16x16x32_bf16(ka0, qf0, dv, 0, 0, 0);
        dv = __builtin_amdgcn_mfma_f32_16x16x32_bf16(ka1, qf1, dv, 0, 0, 0);
        float s0 = dv[0] * 0.125f, s1 = dv[1] * 0.125f;
        float s2 = dv[2] * 0.125f, s3 = dv[3] * 0.125f;
        const bool v0 = !dg || vm[0], v1 = !dg || vm[1];
        const bool v2 = !dg || vm[2], v3 = !dg || vm[3];
        float kmax = fmaxf(fmaxf(v0 ? s0 : -3.0e38f, v1 ? s1 : -3.0e38f),
                           fmaxf(v2 ? s2 : -3.0e38f, v3 ? s3 : -3.0e38f));
        float nm = fmaxf(mrun, kmax);
        Srun *= __expf(mrun - nm);
        float e0 = v0 ? __expf(s0 - nm) : 0.f;
        float e1 = v1 ? __expf(s1 - nm) : 0.f;
        float e2 = v2 ? __expf(s2 - nm) : 0.f;
        float e3 = v3 ? __expf(s3 - nm) : 0.f;
        Srun += (e0 + e1) + (e2 + e3);
        mrun = nm;
      }
    }
    const float m1 = redmax2(mrun);
    const float S1 = redsum2(Srun * __expf(mrun - m1));
    const float inv1 = (S1 > 0.f) ? (1.f / S1) : 0.f;
    const float M2p  = fmaxf(m1, 0.f);

    f32x4 oacc[4] = {};
    float cbase = 0.f, S2l = 0.f;
    const float qlf = (float)(i0 + ql);

    auto subkt = [&](int kt, bool dg, u32& wA, u32& wB) {
      const int krow = kt * 16 + ql;
      const int ksw  = (krow & 7) << 4;
      bf16x8 ka0 = *(const bf16x8*)(kSb + ((krow * 128      + g * 16) ^ ksw));
      bf16x8 ka1 = *(const bf16x8*)(kSb + ((krow * 128 + 64 + g * 16) ^ ksw));
      f32x4 dv = {};
      dv = __builtin_amdgcn_mfma_f32_16x16x32_bf16(ka0, qf0, dv, 0, 0, 0);
      dv = __builtin_amdgcn_mfma_f32_16x16x32_bf16(ka1, qf1, dv, 0, 0, 0);
      float sv[4];
      sv[0] = dv[0] * 0.125f; sv[1] = dv[1] * 0.125f;
      sv[2] = dv[2] * 0.125f; sv[3] = dv[3] * 0.125f;
      const bool v0 = !dg || vm[0], v1 = !dg || vm[1];
      const bool v2 = !dg || vm[2], v3 = !dg || vm[3];
      float e0 = v0 ? __expf(sv[0] - m1) : 0.f;
      float e1 = v1 ? __expf(sv[1] - m1) : 0.f;
      float e2 = v2 ? __expf(sv[2] - m1) : 0.f;
      float e3 = v3 ? __expf(sv[3] - m1) : 0.f;
      float p0 = e0, p1 = p0 + e1, p2 = p1 + e2, p3 = p2 + e3;
      float a16 = __shfl_up(p3, 16, 64);
      float a32 = __shfl_up(p3, 32, 64);
      float a48 = __shfl_up(p3, 48, 64);
      float gp = (g >= 1 ? a16 : 0.f) + (g >= 2 ? a32 : 0.f) + (g >= 3 ? a48 : 0.f);
      float tt = __shfl(gp + p3, ql + 48, 64);
      const float pbase = cbase + gp;
      const float pf = qlf - (float)(kt * 16 + 4 * g);
      float ipr[4] = {p0, p1, p2, p3};
      bool  vv[4]  = {v0, v1, v2, v3};
      float q2[4];
      #pragma unroll
      for (int rg = 0; rg < 4; ++rg) {
        float rem  = fmaxf((S1 - (pbase + ipr[rg])) * inv1, 0.f);
        float pos  = pf - (float)rg;
        float dist = sqrtf(fmaxf(rem * pos, 0.f));
        float eff  = fmaxf(__expf(gamma * dist), 1e-5f);
        float s2v  = sv[rg] * eff;
        float ee   = vv[rg] ? __expf(s2v - M2p) : 0.f;
        q2[rg] = ee;
        S2l += ee;
      }
      wA = packbf2(q2[0], q2[1]);
      wB = packbf2(q2[2], q2[3]);
      cbase += tt;
    };

    #pragma unroll
    for (int c = 0; c < 16; ++c) {
      if (2 * c <= rs) {
        u32 w0 = 0, w1 = 0, w2 = 0, w3 = 0;
        subkt(2 * c, (2 * c == rs), w0, w1);
        if (2 * c + 1 <= rs) subkt(2 * c + 1, (2 * c + 1 == rs), w2, w3);
        *(u32*)(pB + ((ql * 64 +      8 * g    ) ^ swp)) = w0;
        *(u32*)(pB + ((ql * 64 +      8 * g + 4) ^ swp)) = w1;
        *(u32*)(pB + ((ql * 64 + 32 + 8 * g    ) ^ swp)) = w2;
        *(u32*)(pB + ((ql * 64 + 32 + 8 * g + 4) ^ swp)) = w3;
        bf16x8 pa = *(const bf16x8*)(pB + ((ql * 64 + 16 * g) ^ swp));
        #pragma unroll
        for (int n = 0; n < 4; ++n) {
          bf16x8 vb = *(const bf16x8*)(vTb + vbase[n] + ((64 * c + 16 * g) ^ vsw[n]));
          oacc[n] = __builtin_amdgcn_mfma_f32_16x16x32_bf16(pa, vb, oacc[n], 0, 0, 0);
        }
      }
    }

    const float S2   = redsum2(S2l);
    const float inv2 = 1.f / fmaxf(S2, 1e-30f);
    float i2[4];
    #pragma unroll
    for (int rg = 0; rg < 4; ++rg) i2[rg] = __shfl(inv2, 4 * g + rg, 64);

    #pragma unroll
    for (int n = 0; n < 4; ++n) {
      #pragma unroll
      for (int rg = 0; rg < 4; ++rg) {
        const int qo = i0 + 4 * g + rg;
        float val = oacc[n][rg] * i2[rg];
        if (zero_pad && qo == 0) val = 0.f;
        out[base + (size_t)qo * DDIM + n * 16 + ql] = pack1bf(val);
      }
    }
  }
}

// ---------- fused residual + LayerNorm: out = LN(a + b [+ c]) ----------
__global__ __launch_bounds__(256) void ln_kernel(
    const float* __restrict__ a, const float* __restrict__ bsrc,
    const float* __restrict__ csrc,
    const float* __restrict__ g, const float* __restrict__ be,
    float* __restrict__ outF, u16* __restrict__ outB)
{
  const int lane = threadIdx.x & 63, w = threadIdx.x >> 6;
  const size_t row = (size_t)blockIdx.x * 4 + w;
  const float* pa = a    + row * DDIM;
  const float* pb = bsrc + row * DDIM;
  const float* pc = csrc ? csrc + row * DDIM : nullptr;
  float v[8];
  float sum = 0.f;
  #pragma unroll
  for (int c = 0; c < 2; ++c) {
    float4 va = *(const float4*)(pa + c * 256 + lane * 4);
    float4 vb = *(const float4*)(pb + c * 256 + lane * 4);
    v[c*4+0] = va.x + vb.x; v[c*4+1] = va.y + vb.y;
    v[c*4+2] = va.z + vb.z; v[c*4+3] = va.w + vb.w;
    if (pc) {
      float4 vc = *(const float4*)(pc + c * 256 + lane * 4);
      v[c*4+0] += vc.x; v[c*4+1] += vc.y; v[c*4+2] += vc.z; v[c*4+3] += vc.w;
    }
    sum += v[c*4+0] + v[c*4+1] + v[c*4+2] + v[c*4+3];
  }
  #pragma unroll
  for (int off = 32; off > 0; off >>= 1) sum += __shfl_xor(sum, off, 64);
  const float mean = sum * (1.f / 512.f);
  float var = 0.f;
  #pragma unroll
  for (int k = 0; k < 8; ++k) { float dd = v[k] - mean; var = fmaf(dd, dd, var); }
  #pragma unroll
  for (int off = 32; off > 0; off >>= 1) var += __shfl_xor(var, off, 64);
  var *= (1.f / 512.f);
  const float inv = rsqrtf(var + 1e-5f);
  #pragma unroll
  for (int c = 0; c < 2; ++c) {
    float4 gg = *(const float4*)(g  + c * 256 + lane * 4);
    float4 bb = *(const float4*)(be + c * 256 + lane * 4);
    float4 o;
    o.x = (v[c*4+0] - mean) * inv * gg.x + bb.x;
    o.y = (v[c*4+1] - mean) * inv * gg.y + bb.y;
    o.z = (v[c*4+2] - mean) * inv * gg.z + bb.z;
    o.w = (v[c*4+3] - mean) * inv * gg.w + bb.w;
    const size_t off4 = row * DDIM + c * 256 + lane * 4;
    if (outF) *(float4*)(outF + off4) = o;
    if (outB) {
      uint2 p;
      p.x = packbf2(o.x, o.y); p.y = packbf2(o.z, o.w);
      *(uint2*)(outB + off4) = p;
    }
  }
}

// ---------- orchestration ----------
extern "C" void kernel_launch(void* const* d_in, const int* in_sizes, int n_in,
                              void* d_out, int out_size, void* d_ws, size_t ws_size,
                              hipStream_t stream) {
  const float* qe  = (const float*)d_in[0];
  const float* qa  = (const float*)d_in[1];
  const float* Wk  = (const float*)d_in[2];
  const float* bk  = (const float*)d_in[3];
  const float* Wv  = (const float*)d_in[4];
  const float* bv  = (const float*)d_in[5];
  const float* Wo  = (const float*)d_in[6];
  const float* bo  = (const float*)d_in[7];
  const float* gm  = (const float*)d_in[8];
  const float* l1g = (const float*)d_in[9];
  const float* l1b = (const float*)d_in[10];
  const float* W1  = (const float*)d_in[11];
  const float* b1  = (const float*)d_in[12];
  const float* W2  = (const float*)d_in[13];
  const float* b2  = (const float*)d_in[14];
  const float* l2g = (const float*)d_in[15];
  const float* l2b = (const float*)d_in[16];

  char* ws = (char*)d_ws;
  u16* WT = (u16*)ws;                              // 17.3 MB packed weights
  u16* A0 = (u16*)(ws + ((size_t)18  << 20));      // 16 MiB bf16 act slots
  u16* A1 = (u16*)(ws + ((size_t)34  << 20));
  u16* A2 = (u16*)(ws + ((size_t)50  << 20));
  u16* A3 = (u16*)(ws + ((size_t)66  << 20));
  float* F0 = (float*)(ws + ((size_t)82  << 20));  // 32 MiB f32 slot
  float* F1 = (float*)(ws + ((size_t)114 << 20));  // 32 MiB f32 slot
  u16* Amid = (u16*)(ws + ((size_t)146 << 20));    // 64 MiB FFN mid
  float* PWo = (float*)Amid;                        // Wo split-K partial (aliases Amid; disjoint lifetime)
  float* PW2 = (float*)A2;                          // W2 split-K partial (aliases A2+A3; dead there)

  u16* WkT = WT;                    // [L][512][512]
  u16* WvT = WT + (size_t)3 * 262144;
  u16* WoT = WT + (size_t)6 * 262144;
  u16* W1T = WT + (size_t)9 * 262144;              // [L][2048][512]
  u16* W2T = W1T + (size_t)3 * 1048576;            // [L][512][2048]

  pack_w_t<<<dim3(8, 8, 3),  256, 0, stream>>>(Wk, WkT, 512, 512);
  pack_w_t<<<dim3(8, 8, 3),  256, 0, stream>>>(Wv, WvT, 512, 512);
  pack_w_t<<<dim3(8, 8, 3),  256, 0, stream>>>(Wo, WoT, 512, 512);
  pack_w_t<<<dim3(32, 8, 3), 256, 0, stream>>>(W1, W1T, 512, 2048);
  pack_w_t<<<dim3(8, 32, 3), 256, 0, stream>>>(W2, W2T, 2048, 512);
  pack_flat<<<4096, 256, 0, stream>>>(qa, A0);
  pack_flat<<<4096, 256, 0, stream>>>(qe, A1);

  // g8: N,M in elements; nz=2 -> dual pointer sets (batch or split-K)
  auto g8 = [&](const u16* Aa, const u16* Ab, int lda,
                const u16* Ba, const u16* Bb, int ldb,
                const float* ba, const float* bb,
                float* oFa, float* oFb, u16* oBa, u16* oBb,
                int ldc, int M, int N, int Kz, int relu, int nz) {
    gemm8<<<dim3(N / 256, M / 256, nz), 512, 0, stream>>>(
        Aa, Ab, lda, Ba, Bb, ldb, ba, bb, oFa, oFb, oBa, oBb, ldc, Kz, relu);
  };

  auto layer = [&](int li, const u16* qbf, const float* qf32, const u16* vbf,
                   int excl, int zp, int pos,
                   float* lnF, u16* lnB, float* y2F, u16* y2B) {
    const float* bk_l = bk + (size_t)li * DDIM;
    const float* bv_l = bv + (size_t)li * DDIM;
    const float* bo_l = bo + (size_t)li * DDIM;
    const float* gm_l = gm + (size_t)li * HH;
    const float* g1   = l1g + (size_t)li * DDIM;
    const float* be1  = l1b + (size_t)li * DDIM;
    const float* g2   = l2g + (size_t)li * DDIM;
    const float* be2  = l2b + (size_t)li * DDIM;
    const float* b1_l = b1 + (size_t)li * DFFN;
    const float* b2_l = b2 + (size_t)li * DDIM;
    const u16* WkT_l = WkT + (size_t)li * 262144;
    const u16* WvT_l = WvT + (size_t)li * 262144;
    const u16* WoT_l = WoT + (size_t)li * 262144;
    const u16* W1T_l = W1T + (size_t)li * 1048576;
    const u16* W2T_l = W2T + (size_t)li * 1048576;

    // fused qk + v projections (z-batched)
    g8(qbf, vbf, 512, WkT_l, WvT_l, 512, bk_l, bv_l,
       nullptr, nullptr, A2, A3, 512, MR, 512, 512, 0, 2);
    attn_mfma<<<BB * HH, 512, 0, stream>>>(A2, A3, gm_l, A3, excl, zp);
    // Wo: split-K (z0: k<256 +bias -> F0; z1: k>=256 -> PWo)
    g8(A3, A3 + 256, 512, WoT_l, WoT_l + 256, 512, bo_l, nullptr,
       F0, PWo, nullptr, nullptr, 512, MR, 512, 256, 0, 2);
    ln_kernel<<<MR / 4, 256, 0, stream>>>(qf32, F0, PWo, g1, be1, lnF, lnB);
    if (pos) {
      // FFN W1: N=2048, relu, bf16 mid
      g8(lnB, nullptr, 512, W1T_l, nullptr, 512, b1_l, nullptr,
         nullptr, nullptr, Amid, nullptr, 2048, MR, 2048, 512, 1, 1);
      // FFN W2: split-K over 2048 (z0 +bias -> F0; z1 -> PW2)
      g8(Amid, Amid + 1024, 2048, W2T_l, W2T_l + 1024, 2048, b2_l, nullptr,
         F0, PW2, nullptr, nullptr, 512, MR, 512, 1024, 0, 2);
      ln_kernel<<<MR / 4, 256, 0, stream>>>(lnF, F0, PW2, g2, be2, y2F, y2B);
    }
  };

  // layer 0: self-attn on qa, incl mask, FFN -> y1 (bf16 in A0)
  layer(0, A0, qa, A0, 0, 0, 1, F1, A2, nullptr, A0);
  // layer 1: self-attn on qe, incl mask, no FFN -> x1 (f32 F1, bf16 A1)
  layer(1, A1, qe, A1, 0, 0, 0, F1, A1, nullptr, nullptr);
  // layer 2: cross-attn (q = x1, values = y1), strict mask, zero_pad, FFN -> d_out
  layer(2, A1, F1, A0, 1, 1, 1, F1, A1, (float*)d_out, nullptr);
}